// Round 3
// baseline (823.200 us; speedup 1.0000x reference)
//
#include <hip/hip_runtime.h>
#include <hip/hip_bf16.h>
#include <math.h>

typedef __attribute__((ext_vector_type(8))) short bf16x8;
typedef __attribute__((ext_vector_type(4))) float f32x4;

__device__ __forceinline__ unsigned short f2b(float f) {
  unsigned u = __float_as_uint(f);
  unsigned r = (u + 0x7FFF + ((u >> 16) & 1)) >> 16;
  return (unsigned short)r;
}

__device__ __forceinline__ void async16(const void* g, void* l) {
  __builtin_amdgcn_global_load_lds(
      (const __attribute__((address_space(1))) unsigned int*)(g),
      (__attribute__((address_space(3))) unsigned int*)(l), 16, 0, 0);
}

__device__ __forceinline__ void async4(const void* g, void* l) {
  __builtin_amdgcn_global_load_lds(
      (const __attribute__((address_space(1))) unsigned int*)(g),
      (__attribute__((address_space(3))) unsigned int*)(l), 4, 0, 0);
}

// Sum across the 16 lanes of a DPP row (lanes 16k..16k+15) via row_ror.
__device__ __forceinline__ float rowsum16(float x) {
  x += __int_as_float(__builtin_amdgcn_update_dpp(0, __float_as_int(x), 0x121, 0xF, 0xF, false));
  x += __int_as_float(__builtin_amdgcn_update_dpp(0, __float_as_int(x), 0x122, 0xF, 0xF, false));
  x += __int_as_float(__builtin_amdgcn_update_dpp(0, __float_as_int(x), 0x124, 0xF, 0xF, false));
  x += __int_as_float(__builtin_amdgcn_update_dpp(0, __float_as_int(x), 0x128, 0xF, 0xF, false));
  return x;
}

// ---------------------------------------------------------------------------
// fp32 -> bf16 converts: x,R,K,V fused (R/K/V into one concatenated 3072x2048).
// ---------------------------------------------------------------------------
__global__ __launch_bounds__(256) void cvt4_kernel(
    const float* __restrict__ x, const float* __restrict__ R,
    const float* __restrict__ K, const float* __restrict__ V,
    unsigned short* __restrict__ xb, unsigned short* __restrict__ RKVb)
{
  const int bid = blockIdx.x;
  const float* s; unsigned short* d; int i;
  if (bid < 8192)       { s = x; d = xb; i = bid * 256 + threadIdx.x; }
  else if (bid < 12288) { s = R; d = RKVb; i = (bid - 8192) * 256 + threadIdx.x; }
  else if (bid < 13312) { s = K; d = RKVb + 2048 * 2048; i = (bid - 12288) * 256 + threadIdx.x; }
  else                  { s = V; d = RKVb + 2560 * 2048; i = (bid - 13312) * 256 + threadIdx.x; }
  float4 v = ((const float4*)s)[i];
  ushort4 o;
  o.x = f2b(v.x); o.y = f2b(v.y); o.z = f2b(v.z); o.w = f2b(v.w);
  ((ushort4*)d)[i] = o;
}

__global__ __launch_bounds__(256) void cvt_bf16(
    const float* __restrict__ s, unsigned short* __restrict__ d, int n4)
{
  int i = blockIdx.x * 256 + threadIdx.x;
  if (i < n4) {
    float4 v = ((const float4*)s)[i];
    ushort4 o;
    o.x = f2b(v.x); o.y = f2b(v.y); o.z = f2b(v.z); o.w = f2b(v.w);
    ((ushort4*)d)[i] = o;
  }
}

// ---------------------------------------------------------------------------
// Transposed converts, all 6 small matrices in ONE launch (192 blocks):
// out[n*ors + k] = bf16(in[k*Nd + n]).
// ---------------------------------------------------------------------------
__global__ __launch_bounds__(256) void tcvt_all(
    const float* __restrict__ w1, const float* __restrict__ a1,
    const float* __restrict__ v1, const float* __restrict__ w2,
    const float* __restrict__ a2, const float* __restrict__ v2,
    unsigned short* __restrict__ Bcat, unsigned short* __restrict__ w2t,
    unsigned short* __restrict__ a2t, unsigned short* __restrict__ v2t)
{
  const int r = blockIdx.x >> 5, i = blockIdx.x & 31;
  const float* in; unsigned short* out; int Kd, Nd, ors, bx, by;
  switch (r) {
    case 0:  in = w1; out = Bcat;             Kd = 2048; Nd = 64;   ors = 2048; bx = 0; by = i; break;
    case 1:  in = a1; out = Bcat + 64 * 2048; Kd = 2048; Nd = 64;   ors = 2048; bx = 0; by = i; break;
    case 2:  in = v1; out = Bcat + 128 * 2048; Kd = 2048; Nd = 32;  ors = 2048; bx = 0; by = i; break;
    case 3:  in = w2; out = w2t;              Kd = 64;   Nd = 2048; ors = 64;   bx = i; by = 0; break;
    case 4:  in = a2; out = a2t;              Kd = 64;   Nd = 2048; ors = 64;   bx = i; by = 0; break;
    default: in = v2; out = v2t;              Kd = 32;   Nd = 2048; ors = 32;   bx = i; by = 0; break;
  }
  __shared__ unsigned short tile[64][65];
  const int tx = threadIdx.x & 63, ty = threadIdx.x >> 6;
  const int n0 = bx * 64, k0 = by * 64;
  #pragma unroll
  for (int j = 0; j < 16; ++j) {
    const int k = k0 + j * 4 + ty;
    const int n = n0 + tx;
    unsigned short v = 0;
    if (k < Kd && n < Nd) v = f2b(in[(size_t)k * Nd + n]);
    tile[j * 4 + ty][tx] = v;
  }
  __syncthreads();
  #pragma unroll
  for (int j = 0; j < 16; ++j) {
    const int n = n0 + j * 4 + ty;
    const int k = k0 + tx;
    if (n < Nd && k < Kd) out[(size_t)n * ors + k] = tile[tx][j * 4 + ty];
  }
}

// ---------------------------------------------------------------------------
// bf16 MFMA GEMM: C[M,N] = A[M,K] @ B[N,K]^T (+bias). 128x128 tile, BK=32.
// ---------------------------------------------------------------------------
template<int OUTBF16, int ACT>
__global__ __launch_bounds__(256) void gemm_mfma(
    const unsigned short* __restrict__ A, int lda,
    const unsigned short* __restrict__ B, int ldb,
    const float* __restrict__ bias, void* __restrict__ Cv, int ldc,
    int M, int N, int K)
{
  __shared__ __align__(16) unsigned short As[128 * 32];
  __shared__ __align__(16) unsigned short Bs[128 * 32];
  const int tid = threadIdx.x;
  const int w = tid >> 6, lane = tid & 63;
  const int wr = (w >> 1) * 64, wc = (w & 1) * 64;
  const int row0 = blockIdx.y * 128, col0 = blockIdx.x * 128;

  f32x4 acc[4][4];
  #pragma unroll
  for (int i = 0; i < 4; ++i)
    #pragma unroll
    for (int j = 0; j < 4; ++j)
      acc[i][j] = (f32x4){0.f, 0.f, 0.f, 0.f};

  const int srow = w * 32 + (lane >> 2);
  const int scol = (lane & 3) * 8;
  const int brow0 = (col0 + srow < N) ? (col0 + srow) : 0;
  const int brow1 = (col0 + srow + 16 < N) ? (col0 + srow + 16) : 0;
  const unsigned short* gA0 = A + (size_t)(row0 + srow) * lda + scol;
  const unsigned short* gA1 = gA0 + (size_t)16 * lda;
  const unsigned short* gB0 = B + (size_t)brow0 * ldb + scol;
  const unsigned short* gB1 = B + (size_t)brow1 * ldb + scol;
  unsigned short* lA0 = As + w * 1024;
  unsigned short* lA1 = As + w * 1024 + 512;
  unsigned short* lB0 = Bs + w * 1024;
  unsigned short* lB1 = Bs + w * 1024 + 512;

  const int m16 = lane & 15;
  const int q8  = (lane >> 4) * 8;

  for (int k0 = 0; k0 < K; k0 += 32) {
    async16(gA0, lA0);
    async16(gA1, lA1);
    async16(gB0, lB0);
    async16(gB1, lB1);
    gA0 += 32; gA1 += 32; gB0 += 32; gB1 += 32;
    __syncthreads();
    bf16x8 af[4], bfr[4];
    #pragma unroll
    for (int i = 0; i < 4; ++i) {
      af[i]  = *(const bf16x8*)(As + (wr + i * 16 + m16) * 32 + q8);
      bfr[i] = *(const bf16x8*)(Bs + (wc + i * 16 + m16) * 32 + q8);
    }
    #pragma unroll
    for (int i = 0; i < 4; ++i)
      #pragma unroll
      for (int j = 0; j < 4; ++j)
        acc[i][j] = __builtin_amdgcn_mfma_f32_16x16x32_bf16(af[i], bfr[j], acc[i][j], 0, 0, 0);
    __syncthreads();
  }

  #pragma unroll
  for (int j = 0; j < 4; ++j) {
    const int c_ = col0 + wc + j * 16 + (lane & 15);
    if (c_ < N) {
      const float bv = bias ? bias[c_] : 0.f;
      #pragma unroll
      for (int i = 0; i < 4; ++i) {
        const int r_ = row0 + wr + i * 16 + (lane >> 4) * 4;
        #pragma unroll
        for (int t4 = 0; t4 < 4; ++t4) {
          float v = acc[i][j][t4] + bv;
          if (ACT == 2 && c_ < 64) v = tanhf(v);
          if (OUTBF16)
            ((unsigned short*)Cv)[(size_t)(r_ + t4) * ldc + c_] = f2b(v);
          else
            ((float*)Cv)[(size_t)(r_ + t4) * ldc + c_] = v;
        }
      }
    }
  }
}

// ---------------------------------------------------------------------------
// Merged R|K|V projection GEMM: B is the concatenated (3072 x 2048) weight.
// ---------------------------------------------------------------------------
__global__ __launch_bounds__(256) void gemm_rkv(
    const unsigned short* __restrict__ A, const unsigned short* __restrict__ B,
    const float* __restrict__ Rb_, const float* __restrict__ Kb_,
    const float* __restrict__ Vb_,
    float* __restrict__ Cr, float* __restrict__ Ck, float* __restrict__ Cvv)
{
  __shared__ __align__(16) unsigned short As[128 * 32];
  __shared__ __align__(16) unsigned short Bs[128 * 32];
  const int tid = threadIdx.x;
  const int w = tid >> 6, lane = tid & 63;
  const int wr = (w >> 1) * 64, wc = (w & 1) * 64;
  const int row0 = blockIdx.y * 128, col0 = blockIdx.x * 128;

  float* Cd; int ldc, cbase; const float* bias;
  if (col0 < 2048)      { Cd = Cr;  ldc = 2048; cbase = col0;        bias = Rb_; }
  else if (col0 < 2560) { Cd = Ck;  ldc = 512;  cbase = col0 - 2048; bias = Kb_; }
  else                  { Cd = Cvv; ldc = 512;  cbase = col0 - 2560; bias = Vb_; }

  f32x4 acc[4][4];
  #pragma unroll
  for (int i = 0; i < 4; ++i)
    #pragma unroll
    for (int j = 0; j < 4; ++j)
      acc[i][j] = (f32x4){0.f, 0.f, 0.f, 0.f};

  const int srow = w * 32 + (lane >> 2);
  const int scol = (lane & 3) * 8;
  const unsigned short* gA0 = A + (size_t)(row0 + srow) * 2048 + scol;
  const unsigned short* gA1 = gA0 + (size_t)16 * 2048;
  const unsigned short* gB0 = B + (size_t)(col0 + srow) * 2048 + scol;
  const unsigned short* gB1 = gB0 + (size_t)16 * 2048;
  unsigned short* lA0 = As + w * 1024;
  unsigned short* lA1 = As + w * 1024 + 512;
  unsigned short* lB0 = Bs + w * 1024;
  unsigned short* lB1 = Bs + w * 1024 + 512;

  const int m16 = lane & 15;
  const int q8  = (lane >> 4) * 8;

  for (int k0 = 0; k0 < 2048; k0 += 32) {
    async16(gA0, lA0);
    async16(gA1, lA1);
    async16(gB0, lB0);
    async16(gB1, lB1);
    gA0 += 32; gA1 += 32; gB0 += 32; gB1 += 32;
    __syncthreads();
    bf16x8 af[4], bfr[4];
    #pragma unroll
    for (int i = 0; i < 4; ++i) {
      af[i]  = *(const bf16x8*)(As + (wr + i * 16 + m16) * 32 + q8);
      bfr[i] = *(const bf16x8*)(Bs + (wc + i * 16 + m16) * 32 + q8);
    }
    #pragma unroll
    for (int i = 0; i < 4; ++i)
      #pragma unroll
      for (int j = 0; j < 4; ++j)
        acc[i][j] = __builtin_amdgcn_mfma_f32_16x16x32_bf16(af[i], bfr[j], acc[i][j], 0, 0, 0);
    __syncthreads();
  }

  #pragma unroll
  for (int j = 0; j < 4; ++j) {
    const int c_ = cbase + wc + j * 16 + (lane & 15);
    const float bv = bias[c_];
    #pragma unroll
    for (int i = 0; i < 4; ++i) {
      const int r_ = row0 + wr + i * 16 + (lane >> 4) * 4;
      #pragma unroll
      for (int t4 = 0; t4 < 4; ++t4)
        Cd[(size_t)(r_ + t4) * ldc + c_] = acc[i][j][t4] + bv;
    }
  }
}

// ---------------------------------------------------------------------------
// Elementwise prep (unchanged).
// ---------------------------------------------------------------------------
__global__ __launch_bounds__(256) void prep_kernel(
    const float* __restrict__ k_buf, const float* __restrict__ v_buf,
    float* wt_decay, const float* __restrict__ at, float* vt_vf,
    const float* __restrict__ v_first,
    const float* __restrict__ w0, const float* __restrict__ a0,
    const float* __restrict__ v0, const float* __restrict__ k_k,
    const float* __restrict__ k_a,
    float* __restrict__ kf, float* __restrict__ aaq, float* __restrict__ bbq)
{
  const int row = blockIdx.x;
  const int tid = threadIdx.x;
  const int c0 = tid << 3;
  const int h = tid >> 3;
  const int kvoff = (h >> 2) << 6;
  const size_t base = (size_t)row * 2048;
  const size_t kvrow = (size_t)row * 512;
  float kr[8], kkr[8];
  float ss = 0.f;
  #pragma unroll
  for (int e = 0; e < 8; ++e) {
    const int c = c0 + e;
    const float kv = k_buf[kvrow + kvoff + (c & 63)];
    kr[e] = kv;
    const float t = kv * k_k[c];
    kkr[e] = t;
    ss = fmaf(t, t, ss);
  }
  ss += __shfl_xor(ss, 1);
  ss += __shfl_xor(ss, 2);
  ss += __shfl_xor(ss, 4);
  const float inv = 1.f / fmaxf(sqrtf(ss), 1e-12f);
  #pragma unroll
  for (int e = 0; e < 8; ++e) {
    const int c = c0 + e;
    const size_t idx = base + c;
    const float kk = kkr[e] * inv;
    const float a = 1.f / (1.f + expf(-(a0[c] + at[idx])));
    const float u = w0[c] + wt_decay[idx];
    const float sig_u = 1.f / (1.f + expf(-u));
    wt_decay[idx] = expf(-0.5488116360940264f * sig_u);
    kf[idx] = kr[e] * fmaf(a - 1.f, k_a[c], 1.f);
    const float vr = v_buf[kvrow + kvoff + (c & 63)];
    const float sv = 1.f / (1.f + expf(-(v0[c] + vt_vf[idx])));
    vt_vf[idx] = vr + (v_first[idx] - vr) * sv;
    aaq[idx] = -kk;
    bbq[idx] = kk * a;
  }
}

// ---------------------------------------------------------------------------
// RWKV-7 scan — cooperative-LDS, 2-rows-per-lane version.
//
// 256 blocks (1/CU): block = (bh, 32-row half). 4 waves x 8 rows; lane
// (rg,colg) holds S[r0..r0+1][4colg..+3] (r0 = half*32 + widx*8 + rg*2).
// Each stream float4 read from LDS serves TWO rows -> LDS traffic per CU
// halves vs round-2 (was the binding 514 cyc/step; model now ~270).
// Streams staged per block (2 copies/bh instead of 4). Double-buffered,
// counted vmcnt (STAGE=7 ops, YSTORE=1 -> WB(7)/WB(8)/WB(1)); lgkmcnt(0)
// added to WB to close the YSTORE-read vs next-PROCESS-write y_lds race.
// GroupNorm partial sums (Sum y, Sum y^2) are accumulated in-scan and
// written per (bh,half) -> gsum kernel eliminated.
// ---------------------------------------------------------------------------
#define WB(n) asm volatile("s_waitcnt vmcnt(" #n ") lgkmcnt(0)\n\ts_barrier" ::: "memory")
#define BAR2() asm volatile("s_waitcnt lgkmcnt(0)\n\ts_barrier" ::: "memory")

__global__ __launch_bounds__(256) void scan_kernel(
    const float* __restrict__ rB, const float* __restrict__ dB,
    const float* __restrict__ kB, const float* __restrict__ vB,
    const float* __restrict__ aB, const float* __restrict__ bB,
    const float* __restrict__ state, float* __restrict__ y,
    float* __restrict__ part)
{
  // LDS floats: buf[p] at p*5632: r,d,k,a,b at +0..+4096 ([16 steps][64]),
  // v at +5120 ([16 steps][32 rows]). y at 11264 ([16][32]). Total 11776.
  __shared__ float lds[11776];
  const int tid = threadIdx.x;
  const int bid = blockIdx.x;
  // XCD swizzle: both blocks of a bh land on XCD (bid&7).
  const int xcd = bid & 7, j = bid >> 3;
  const int half = j & 1, bhq = j >> 1;
  const int bh = (bhq << 3) | xcd;
  const int widx = tid >> 6;
  const int lane = tid & 63;
  const int rg = lane >> 4;
  const int colg = lane & 15;
  const int r0b = (widx << 3) + (rg << 1);   // block-local row in [0,32)
  const int r0 = (half << 5) + r0b;          // global row in [0,64)
  const int b = bh >> 5, h = bh & 31;

  float4 S0 = *(const float4*)(state + (size_t)bh * 4096 + r0 * 64 + (colg << 2));
  float4 S1 = *(const float4*)(state + (size_t)bh * 4096 + (r0 + 1) * 64 + (colg << 2));

  const unsigned cb = (unsigned)((b * 1024) * 2048 + h * 64);
  const unsigned gcol = (unsigned)(colg << 2);
  const unsigned ldsseg = (unsigned)(widx << 8);   // wave's 256-float stream seg
  const unsigned vrow = (unsigned)(half << 5);

  float sacc = 0.f, ssacc = 0.f;

  #define STAGE(step0, bofs) do {                                            \
    const unsigned go_ = cb + (unsigned)((step0) + (tid >> 4)) * 2048u;      \
    async16(rB + go_ + gcol, lds + (bofs) + 0 * 1024 + ldsseg);              \
    async16(dB + go_ + gcol, lds + (bofs) + 1 * 1024 + ldsseg);              \
    async16(kB + go_ + gcol, lds + (bofs) + 2 * 1024 + ldsseg);              \
    async16(aB + go_ + gcol, lds + (bofs) + 3 * 1024 + ldsseg);              \
    async16(bB + go_ + gcol, lds + (bofs) + 4 * 1024 + ldsseg);              \
    const unsigned gv0_ = cb + (unsigned)((step0) + (tid >> 5)) * 2048u      \
                          + vrow + (unsigned)(tid & 31);                     \
    async4(vB + gv0_, lds + (bofs) + 5120 + (widx << 6));                    \
    const unsigned t2_ = (unsigned)tid + 256u;                               \
    const unsigned gv1_ = cb + (unsigned)((step0) + (t2_ >> 5)) * 2048u      \
                          + vrow + (unsigned)(t2_ & 31);                     \
    async4(vB + gv1_, lds + (bofs) + 5120 + 256 + (widx << 6));              \
  } while (0)

  #define PROCESS(bofs) do {                                                 \
    const int orr_ = (bofs) + 0 * 1024 + (colg << 2);                        \
    const int od_  = (bofs) + 1 * 1024 + (colg << 2);                        \
    const int ok_  = (bofs) + 2 * 1024 + (colg << 2);                        \
    const int oa_  = (bofs) + 3 * 1024 + (colg << 2);                        \
    const int ob_  = (bofs) + 4 * 1024 + (colg << 2);                        \
    const int ov_  = (bofs) + 5120 + r0b;                                    \
    _Pragma("unroll")                                                        \
    for (int s = 0; s < 16; ++s) {                                           \
      const float4 av = *(const float4*)(lds + oa_ + s * 64);                \
      const float4 dv = *(const float4*)(lds + od_ + s * 64);                \
      const float4 bv = *(const float4*)(lds + ob_ + s * 64);                \
      const float4 kv = *(const float4*)(lds + ok_ + s * 64);                \
      const float4 rv = *(const float4*)(lds + orr_ + s * 64);               \
      const float2 vv = *(const float2*)(lds + ov_ + (s << 5));              \
      float t0a = fmaf(S0.y, av.y, S0.x * av.x);                             \
      t0a = fmaf(S0.z, av.z, t0a);                                           \
      t0a = fmaf(S0.w, av.w, t0a);                                           \
      float t0b = fmaf(S1.y, av.y, S1.x * av.x);                             \
      t0b = fmaf(S1.z, av.z, t0b);                                           \
      t0b = fmaf(S1.w, av.w, t0b);                                           \
      const float sa0 = rowsum16(t0a);                                       \
      const float sa1 = rowsum16(t0b);                                       \
      S0.x = fmaf(S0.x, dv.x, fmaf(sa0, bv.x, vv.x * kv.x));                 \
      S0.y = fmaf(S0.y, dv.y, fmaf(sa0, bv.y, vv.x * kv.y));                 \
      S0.z = fmaf(S0.z, dv.z, fmaf(sa0, bv.z, vv.x * kv.z));                 \
      S0.w = fmaf(S0.w, dv.w, fmaf(sa0, bv.w, vv.x * kv.w));                 \
      S1.x = fmaf(S1.x, dv.x, fmaf(sa1, bv.x, vv.y * kv.x));                 \
      S1.y = fmaf(S1.y, dv.y, fmaf(sa1, bv.y, vv.y * kv.y));                 \
      S1.z = fmaf(S1.z, dv.z, fmaf(sa1, bv.z, vv.y * kv.z));                 \
      S1.w = fmaf(S1.w, dv.w, fmaf(sa1, bv.w, vv.y * kv.w));                 \
      float t1a = fmaf(S0.y, rv.y, S0.x * rv.x);                             \
      t1a = fmaf(S0.z, rv.z, t1a);                                           \
      t1a = fmaf(S0.w, rv.w, t1a);                                           \
      float t1b = fmaf(S1.y, rv.y, S1.x * rv.x);                             \
      t1b = fmaf(S1.z, rv.z, t1b);                                           \
      t1b = fmaf(S1.w, rv.w, t1b);                                           \
      const float y0 = rowsum16(t1a);                                        \
      const float y1 = rowsum16(t1b);                                        \
      if (colg == 0) {                                                       \
        *(float2*)(lds + 11264 + (s << 5) + r0b) = make_float2(y0, y1);      \
        sacc += y0 + y1;                                                     \
        ssacc = fmaf(y0, y0, fmaf(y1, y1, ssacc));                           \
      }                                                                      \
    }                                                                        \
  } while (0)

  #define YSTORE(step0) do {                                                 \
    const float2 v_ = *(const float2*)(lds + 11264 + ((tid >> 4) << 5)       \
                                       + ((tid & 15) << 1));                 \
    *(float2*)(y + cb + (unsigned)((step0) + (tid >> 4)) * 2048u             \
               + vrow + (unsigned)((tid & 15) << 1)) = v_;                   \
  } while (0)

  STAGE(0, 0);
  STAGE(16, 5632);

  // chunk 0
  WB(7);
  PROCESS(0);
  BAR2();
  YSTORE(0);
  STAGE(32, 0);

  // chunks 1..62
  for (int c = 1; c <= 62; ++c) {
    const int bofs = (c & 1) ? 5632 : 0;
    WB(8);
    PROCESS(bofs);
    BAR2();
    YSTORE(c << 4);
    if (c < 62) STAGE((c + 2) << 4, bofs);
  }

  // chunk 63
  WB(1);
  PROCESS(5632);
  BAR2();
  YSTORE(1008);

  // groupnorm partial for this (bh, half): lanes {0,16,32,48} hold partials.
  sacc  += __shfl_xor(sacc, 16);
  sacc  += __shfl_xor(sacc, 32);
  ssacc += __shfl_xor(ssacc, 16);
  ssacc += __shfl_xor(ssacc, 32);
  __syncthreads();                     // all stream-buf reads done
  if (lane == 0) { lds[widx] = sacc; lds[4 + widx] = ssacc; }
  __syncthreads();
  if (tid == 0) {
    const float s_  = lds[0] + lds[1] + lds[2] + lds[3];
    const float ss_ = lds[4] + lds[5] + lds[6] + lds[7];
    ((float2*)part)[(bh << 1) + half] = make_float2(s_, ss_);
  }

  #undef STAGE
  #undef PROCESS
  #undef YSTORE
}

// ---------------------------------------------------------------------------
// GroupNorm pass B + bonus: per-(b,t) row, writes xx in bf16.
// ---------------------------------------------------------------------------
__global__ __launch_bounds__(256) void gapply_kernel(
    const float* __restrict__ y, const float* __restrict__ rB,
    const float* __restrict__ kf, const float* __restrict__ vf,
    const float* __restrict__ part, const float* __restrict__ r_k,
    const float* __restrict__ ln_w, const float* __restrict__ ln_b,
    unsigned short* __restrict__ xxb)
{
  const int row = blockIdx.x;        // b*1024 + t
  const int b = row >> 10;
  const int tid = threadIdx.x;
  const int h = tid >> 3;
  const int bh = b * 32 + h;
  float s = 0.f, ss = 0.f;
  #pragma unroll
  for (int j = 0; j < 2; ++j) {
    const float2 pr = ((const float2*)part)[(bh << 1) + j];
    s += pr.x; ss += pr.y;
  }
  const float mean = s * (1.f / 65536.f);
  const float rstd = rsqrtf(ss * (1.f / 65536.f) - mean * mean + 0.00064f);
  const int c0 = tid << 3;
  const size_t base = (size_t)row * 2048 + c0;
  float yv[8], vv[8];
  float p = 0.f;
  #pragma unroll
  for (int e = 0; e < 8; ++e) {
    yv[e] = y[base + e];
    vv[e] = vf[base + e];
    p = fmaf(rB[base + e] * kf[base + e], r_k[c0 + e], p);
  }
  p += __shfl_xor(p, 1);
  p += __shfl_xor(p, 2);
  p += __shfl_xor(p, 4);
  #pragma unroll
  for (int e = 0; e < 8; ++e) {
    const float yn = (yv[e] - mean) * rstd;
    xxb[base + e] = f2b(fmaf(yn, ln_w[c0 + e], ln_b[c0 + e]) + p * vv[e]);
  }
}

// ---------------------------------------------------------------------------
extern "C" void kernel_launch(void* const* d_in, const int* in_sizes, int n_in,
                              void* d_out, int out_size, void* d_ws, size_t ws_size,
                              hipStream_t stream) {
  const float* x       = (const float*)d_in[0];
  const float* v_first = (const float*)d_in[1];
  const float* state   = (const float*)d_in[2];
  const float* Rw      = (const float*)d_in[3];
  const float* R_bias  = (const float*)d_in[4];
  const float* Kw      = (const float*)d_in[5];
  const float* K_bias  = (const float*)d_in[6];
  const float* Vw      = (const float*)d_in[7];
  const float* V_bias  = (const float*)d_in[8];
  const float* Ow      = (const float*)d_in[9];
  const float* O_bias  = (const float*)d_in[10];
  const float* w0      = (const float*)d_in[11];
  const float* w1      = (const float*)d_in[12];
  const float* w2      = (const float*)d_in[13];
  const float* a0      = (const float*)d_in[14];
  const float* a1      = (const float*)d_in[15];
  const float* a2      = (const float*)d_in[16];
  const float* v0      = (const float*)d_in[17];
  const float* v1      = (const float*)d_in[18];
  const float* v2      = (const float*)d_in[19];
  const float* k_k     = (const float*)d_in[20];
  const float* k_a     = (const float*)d_in[21];
  const float* r_k     = (const float*)d_in[22];
  const float* ln_w    = (const float*)d_in[23];
  const float* ln_b    = (const float*)d_in[24];

  float* ws = (float*)d_ws;
  float* r_buf = ws;                    // 8388608
  float* k_buf = r_buf + 8388608;       // 2097152
  float* v_buf = k_buf + 2097152;       // 2097152
  float* wt    = v_buf + 2097152;       // 8388608 (u -> decay in place)
  float* at    = wt    + 8388608;       // 8388608 (a pre-act -> y after scan)
  float* vt    = at    + 8388608;       // 8388608 (v pre-act -> v_final)
  float* kf    = vt    + 8388608;       // 8388608
  float* aaq   = kf    + 8388608;       // 8388608
  float* bbq   = aaq   + 8388608;       // 8388608
  float* part  = bbq   + 8388608;       // 2048 (gnorm partials)
  // bf16 aliases into dead-at-use regions (all 16B-aligned):
  unsigned short* xb   = (unsigned short*)bbq;               // dead until prep
  unsigned short* RKVb = (unsigned short*)kf;                // 3072x2048 bf16
  unsigned short* hcat = (unsigned short*)(kf + 3200000);    // 4096x160 bf16
  unsigned short* Bcat = (unsigned short*)(kf + 3600000);    // 160x2048 bf16
  unsigned short* w2t  = (unsigned short*)(kf + 3800000);    // 2048x64
  unsigned short* a2t  = (unsigned short*)(kf + 3900000);    // 2048x64
  unsigned short* v2t  = (unsigned short*)(kf + 4000000);    // 2048x32
  unsigned short* Ob   = (unsigned short*)wt;                // after scan
  unsigned short* xxb  = (unsigned short*)aaq;               // after scan

  dim3 blk(256);
  // ---- converts ----
  cvt4_kernel<<<14336, blk, 0, stream>>>(x, Rw, Kw, Vw, xb, RKVb);
  tcvt_all<<<192, blk, 0, stream>>>(w1, a1, v1, w2, a2, v2, Bcat, w2t, a2t, v2t);
  // ---- low-rank stage 1 (fused, bf16 out, tanh on w-cols) ----
  gemm_mfma<1,2><<<dim3(2, 32), blk, 0, stream>>>(xb, 2048, Bcat, 2048, nullptr,
                                                  hcat, 160, 4096, 160, 2048);
  // ---- merged R|K|V projection ----
  gemm_rkv<<<dim3(24, 32), blk, 0, stream>>>(xb, RKVb, R_bias, K_bias, V_bias,
                                             r_buf, k_buf, v_buf);
  // ---- low-rank stage 2 ----
  gemm_mfma<0,0><<<dim3(16, 32), blk, 0, stream>>>(hcat, 160, w2t, 64, nullptr,
                                                   wt, 2048, 4096, 2048, 64);
  gemm_mfma<0,0><<<dim3(16, 32), blk, 0, stream>>>(hcat + 64, 160, a2t, 64, nullptr,
                                                   at, 2048, 4096, 2048, 64);
  gemm_mfma<0,0><<<dim3(16, 32), blk, 0, stream>>>(hcat + 128, 160, v2t, 32, nullptr,
                                                   vt, 2048, 4096, 2048, 32);
  // ---- elementwise prep ----
  prep_kernel<<<4096, blk, 0, stream>>>(k_buf, v_buf, wt, at, vt, v_first,
                                        w0, a0, v0, k_k, k_a, kf, aaq, bbq);
  // ---- recurrent scan (2 rows/lane; y reuses `at`; gnorm partials fused) ----
  float* ybuf = at;
  scan_kernel<<<256, blk, 0, stream>>>(r_buf, wt, kf, vt, aaq, bbq, state, ybuf,
                                       part);
  // ---- O weight convert (wt dead after scan) ----
  cvt_bf16<<<4096, blk, 0, stream>>>(Ow, Ob, 1048576);
  // ---- group norm pass B + bonus -> bf16 xx ----
  gapply_kernel<<<4096, blk, 0, stream>>>(ybuf, r_buf, kf, vt, part, r_k,
                                          ln_w, ln_b, xxb);
  // ---- output projection ----
  gemm_mfma<0,0><<<dim3(16, 32), blk, 0, stream>>>(xxb, 2048, Ob, 2048, O_bias,
                                                   (float*)d_out, 2048, 4096, 2048, 2048);
}

// Round 4
// 765.563 us; speedup vs baseline: 1.0753x; 1.0753x over previous
//
#include <hip/hip_runtime.h>
#include <hip/hip_bf16.h>
#include <math.h>

typedef __attribute__((ext_vector_type(8))) short bf16x8;
typedef __attribute__((ext_vector_type(4))) float f32x4;

__device__ __forceinline__ unsigned short f2b(float f) {
  unsigned u = __float_as_uint(f);
  unsigned r = (u + 0x7FFF + ((u >> 16) & 1)) >> 16;
  return (unsigned short)r;
}

__device__ __forceinline__ void async16(const void* g, void* l) {
  __builtin_amdgcn_global_load_lds(
      (const __attribute__((address_space(1))) unsigned int*)(g),
      (__attribute__((address_space(3))) unsigned int*)(l), 16, 0, 0);
}

// Sum across the 16 lanes of a DPP row (lanes 16k..16k+15) via row_ror.
__device__ __forceinline__ float rowsum16(float x) {
  x += __int_as_float(__builtin_amdgcn_update_dpp(0, __float_as_int(x), 0x121, 0xF, 0xF, false));
  x += __int_as_float(__builtin_amdgcn_update_dpp(0, __float_as_int(x), 0x122, 0xF, 0xF, false));
  x += __int_as_float(__builtin_amdgcn_update_dpp(0, __float_as_int(x), 0x124, 0xF, 0xF, false));
  x += __int_as_float(__builtin_amdgcn_update_dpp(0, __float_as_int(x), 0x128, 0xF, 0xF, false));
  return x;
}

// ---------------------------------------------------------------------------
// fp32 -> bf16 converts: x,R,K,V fused (R/K/V into one concatenated 3072x2048).
// ---------------------------------------------------------------------------
__global__ __launch_bounds__(256) void cvt4_kernel(
    const float* __restrict__ x, const float* __restrict__ R,
    const float* __restrict__ K, const float* __restrict__ V,
    unsigned short* __restrict__ xb, unsigned short* __restrict__ RKVb)
{
  const int bid = blockIdx.x;
  const float* s; unsigned short* d; int i;
  if (bid < 8192)       { s = x; d = xb; i = bid * 256 + threadIdx.x; }
  else if (bid < 12288) { s = R; d = RKVb; i = (bid - 8192) * 256 + threadIdx.x; }
  else if (bid < 13312) { s = K; d = RKVb + 2048 * 2048; i = (bid - 12288) * 256 + threadIdx.x; }
  else                  { s = V; d = RKVb + 2560 * 2048; i = (bid - 13312) * 256 + threadIdx.x; }
  float4 v = ((const float4*)s)[i];
  ushort4 o;
  o.x = f2b(v.x); o.y = f2b(v.y); o.z = f2b(v.z); o.w = f2b(v.w);
  ((ushort4*)d)[i] = o;
}

__global__ __launch_bounds__(256) void cvt_bf16(
    const float* __restrict__ s, unsigned short* __restrict__ d, int n4)
{
  int i = blockIdx.x * 256 + threadIdx.x;
  if (i < n4) {
    float4 v = ((const float4*)s)[i];
    ushort4 o;
    o.x = f2b(v.x); o.y = f2b(v.y); o.z = f2b(v.z); o.w = f2b(v.w);
    ((ushort4*)d)[i] = o;
  }
}

// ---------------------------------------------------------------------------
// Transposed converts, all 6 small matrices in ONE launch (192 blocks):
// out[n*ors + k] = bf16(in[k*Nd + n]).
// ---------------------------------------------------------------------------
__global__ __launch_bounds__(256) void tcvt_all(
    const float* __restrict__ w1, const float* __restrict__ a1,
    const float* __restrict__ v1, const float* __restrict__ w2,
    const float* __restrict__ a2, const float* __restrict__ v2,
    unsigned short* __restrict__ Bcat, unsigned short* __restrict__ w2t,
    unsigned short* __restrict__ a2t, unsigned short* __restrict__ v2t)
{
  const int r = blockIdx.x >> 5, i = blockIdx.x & 31;
  const float* in; unsigned short* out; int Kd, Nd, ors, bx, by;
  switch (r) {
    case 0:  in = w1; out = Bcat;             Kd = 2048; Nd = 64;   ors = 2048; bx = 0; by = i; break;
    case 1:  in = a1; out = Bcat + 64 * 2048; Kd = 2048; Nd = 64;   ors = 2048; bx = 0; by = i; break;
    case 2:  in = v1; out = Bcat + 128 * 2048; Kd = 2048; Nd = 32;  ors = 2048; bx = 0; by = i; break;
    case 3:  in = w2; out = w2t;              Kd = 64;   Nd = 2048; ors = 64;   bx = i; by = 0; break;
    case 4:  in = a2; out = a2t;              Kd = 64;   Nd = 2048; ors = 64;   bx = i; by = 0; break;
    default: in = v2; out = v2t;              Kd = 32;   Nd = 2048; ors = 32;   bx = i; by = 0; break;
  }
  __shared__ unsigned short tile[64][65];
  const int tx = threadIdx.x & 63, ty = threadIdx.x >> 6;
  const int n0 = bx * 64, k0 = by * 64;
  #pragma unroll
  for (int j = 0; j < 16; ++j) {
    const int k = k0 + j * 4 + ty;
    const int n = n0 + tx;
    unsigned short v = 0;
    if (k < Kd && n < Nd) v = f2b(in[(size_t)k * Nd + n]);
    tile[j * 4 + ty][tx] = v;
  }
  __syncthreads();
  #pragma unroll
  for (int j = 0; j < 16; ++j) {
    const int n = n0 + j * 4 + ty;
    const int k = k0 + tx;
    if (n < Nd && k < Kd) out[(size_t)n * ors + k] = tile[tx][j * 4 + ty];
  }
}

// ---------------------------------------------------------------------------
// bf16 MFMA GEMM: C[M,N] = A[M,K] @ B[N,K]^T (+bias). 128x128 tile, BK=32.
// ---------------------------------------------------------------------------
template<int OUTBF16, int ACT>
__global__ __launch_bounds__(256) void gemm_mfma(
    const unsigned short* __restrict__ A, int lda,
    const unsigned short* __restrict__ B, int ldb,
    const float* __restrict__ bias, void* __restrict__ Cv, int ldc,
    int M, int N, int K)
{
  __shared__ __align__(16) unsigned short As[128 * 32];
  __shared__ __align__(16) unsigned short Bs[128 * 32];
  const int tid = threadIdx.x;
  const int w = tid >> 6, lane = tid & 63;
  const int wr = (w >> 1) * 64, wc = (w & 1) * 64;
  const int row0 = blockIdx.y * 128, col0 = blockIdx.x * 128;

  f32x4 acc[4][4];
  #pragma unroll
  for (int i = 0; i < 4; ++i)
    #pragma unroll
    for (int j = 0; j < 4; ++j)
      acc[i][j] = (f32x4){0.f, 0.f, 0.f, 0.f};

  const int srow = w * 32 + (lane >> 2);
  const int scol = (lane & 3) * 8;
  const int brow0 = (col0 + srow < N) ? (col0 + srow) : 0;
  const int brow1 = (col0 + srow + 16 < N) ? (col0 + srow + 16) : 0;
  const unsigned short* gA0 = A + (size_t)(row0 + srow) * lda + scol;
  const unsigned short* gA1 = gA0 + (size_t)16 * lda;
  const unsigned short* gB0 = B + (size_t)brow0 * ldb + scol;
  const unsigned short* gB1 = B + (size_t)brow1 * ldb + scol;
  unsigned short* lA0 = As + w * 1024;
  unsigned short* lA1 = As + w * 1024 + 512;
  unsigned short* lB0 = Bs + w * 1024;
  unsigned short* lB1 = Bs + w * 1024 + 512;

  const int m16 = lane & 15;
  const int q8  = (lane >> 4) * 8;

  for (int k0 = 0; k0 < K; k0 += 32) {
    async16(gA0, lA0);
    async16(gA1, lA1);
    async16(gB0, lB0);
    async16(gB1, lB1);
    gA0 += 32; gA1 += 32; gB0 += 32; gB1 += 32;
    __syncthreads();
    bf16x8 af[4], bfr[4];
    #pragma unroll
    for (int i = 0; i < 4; ++i) {
      af[i]  = *(const bf16x8*)(As + (wr + i * 16 + m16) * 32 + q8);
      bfr[i] = *(const bf16x8*)(Bs + (wc + i * 16 + m16) * 32 + q8);
    }
    #pragma unroll
    for (int i = 0; i < 4; ++i)
      #pragma unroll
      for (int j = 0; j < 4; ++j)
        acc[i][j] = __builtin_amdgcn_mfma_f32_16x16x32_bf16(af[i], bfr[j], acc[i][j], 0, 0, 0);
    __syncthreads();
  }

  #pragma unroll
  for (int j = 0; j < 4; ++j) {
    const int c_ = col0 + wc + j * 16 + (lane & 15);
    if (c_ < N) {
      const float bv = bias ? bias[c_] : 0.f;
      #pragma unroll
      for (int i = 0; i < 4; ++i) {
        const int r_ = row0 + wr + i * 16 + (lane >> 4) * 4;
        #pragma unroll
        for (int t4 = 0; t4 < 4; ++t4) {
          float v = acc[i][j][t4] + bv;
          if (ACT == 2 && c_ < 64) v = tanhf(v);
          if (OUTBF16)
            ((unsigned short*)Cv)[(size_t)(r_ + t4) * ldc + c_] = f2b(v);
          else
            ((float*)Cv)[(size_t)(r_ + t4) * ldc + c_] = v;
        }
      }
    }
  }
}

// ---------------------------------------------------------------------------
// Merged R|K|V projection GEMM: B is the concatenated (3072 x 2048) weight.
// ---------------------------------------------------------------------------
__global__ __launch_bounds__(256) void gemm_rkv(
    const unsigned short* __restrict__ A, const unsigned short* __restrict__ B,
    const float* __restrict__ Rb_, const float* __restrict__ Kb_,
    const float* __restrict__ Vb_,
    float* __restrict__ Cr, float* __restrict__ Ck, float* __restrict__ Cvv)
{
  __shared__ __align__(16) unsigned short As[128 * 32];
  __shared__ __align__(16) unsigned short Bs[128 * 32];
  const int tid = threadIdx.x;
  const int w = tid >> 6, lane = tid & 63;
  const int wr = (w >> 1) * 64, wc = (w & 1) * 64;
  const int row0 = blockIdx.y * 128, col0 = blockIdx.x * 128;

  float* Cd; int ldc, cbase; const float* bias;
  if (col0 < 2048)      { Cd = Cr;  ldc = 2048; cbase = col0;        bias = Rb_; }
  else if (col0 < 2560) { Cd = Ck;  ldc = 512;  cbase = col0 - 2048; bias = Kb_; }
  else                  { Cd = Cvv; ldc = 512;  cbase = col0 - 2560; bias = Vb_; }

  f32x4 acc[4][4];
  #pragma unroll
  for (int i = 0; i < 4; ++i)
    #pragma unroll
    for (int j = 0; j < 4; ++j)
      acc[i][j] = (f32x4){0.f, 0.f, 0.f, 0.f};

  const int srow = w * 32 + (lane >> 2);
  const int scol = (lane & 3) * 8;
  const unsigned short* gA0 = A + (size_t)(row0 + srow) * 2048 + scol;
  const unsigned short* gA1 = gA0 + (size_t)16 * 2048;
  const unsigned short* gB0 = B + (size_t)(col0 + srow) * 2048 + scol;
  const unsigned short* gB1 = gB0 + (size_t)16 * 2048;
  unsigned short* lA0 = As + w * 1024;
  unsigned short* lA1 = As + w * 1024 + 512;
  unsigned short* lB0 = Bs + w * 1024;
  unsigned short* lB1 = Bs + w * 1024 + 512;

  const int m16 = lane & 15;
  const int q8  = (lane >> 4) * 8;

  for (int k0 = 0; k0 < 2048; k0 += 32) {
    async16(gA0, lA0);
    async16(gA1, lA1);
    async16(gB0, lB0);
    async16(gB1, lB1);
    gA0 += 32; gA1 += 32; gB0 += 32; gB1 += 32;
    __syncthreads();
    bf16x8 af[4], bfr[4];
    #pragma unroll
    for (int i = 0; i < 4; ++i) {
      af[i]  = *(const bf16x8*)(As + (wr + i * 16 + m16) * 32 + q8);
      bfr[i] = *(const bf16x8*)(Bs + (wc + i * 16 + m16) * 32 + q8);
    }
    #pragma unroll
    for (int i = 0; i < 4; ++i)
      #pragma unroll
      for (int j = 0; j < 4; ++j)
        acc[i][j] = __builtin_amdgcn_mfma_f32_16x16x32_bf16(af[i], bfr[j], acc[i][j], 0, 0, 0);
    __syncthreads();
  }

  #pragma unroll
  for (int j = 0; j < 4; ++j) {
    const int c_ = cbase + wc + j * 16 + (lane & 15);
    const float bv = bias[c_];
    #pragma unroll
    for (int i = 0; i < 4; ++i) {
      const int r_ = row0 + wr + i * 16 + (lane >> 4) * 4;
      #pragma unroll
      for (int t4 = 0; t4 < 4; ++t4)
        Cd[(size_t)(r_ + t4) * ldc + c_] = acc[i][j][t4] + bv;
    }
  }
}

// ---------------------------------------------------------------------------
// Elementwise prep. Now also packs the scan streams:
//   rk_pk[idx] = bf16(k_final)<<16 | bf16(r)      (u32, std [row][2048] layout)
//   ab_pk[idx] = bf16(aa)<<16     | bf16(bb)
// decay (wt, f32 in-place) and v_final (vt, f32 in-place) stay full precision
// (decay compounds multiplicatively over 1024 steps). kf/aaq/bbq std-layout
// f32 buffers are gone; gapply reads r,k from rk_pk.
// ---------------------------------------------------------------------------
__global__ __launch_bounds__(256) void prep_kernel(
    const float* __restrict__ k_buf, const float* __restrict__ v_buf,
    const float* __restrict__ r_buf,
    float* wt_decay, const float* __restrict__ at, float* vt_vf,
    const float* __restrict__ v_first,
    const float* __restrict__ w0, const float* __restrict__ a0,
    const float* __restrict__ v0, const float* __restrict__ k_k,
    const float* __restrict__ k_a,
    unsigned* __restrict__ rk_pk, unsigned* __restrict__ ab_pk)
{
  const int row = blockIdx.x;
  const int tid = threadIdx.x;
  const int c0 = tid << 3;
  const int h = tid >> 3;
  const int kvoff = (h >> 2) << 6;
  const size_t base = (size_t)row * 2048;
  const size_t kvrow = (size_t)row * 512;
  float kr[8], kkr[8];
  float ss = 0.f;
  #pragma unroll
  for (int e = 0; e < 8; ++e) {
    const int c = c0 + e;
    const float kv = k_buf[kvrow + kvoff + (c & 63)];
    kr[e] = kv;
    const float t = kv * k_k[c];
    kkr[e] = t;
    ss = fmaf(t, t, ss);
  }
  ss += __shfl_xor(ss, 1);
  ss += __shfl_xor(ss, 2);
  ss += __shfl_xor(ss, 4);
  const float inv = 1.f / fmaxf(sqrtf(ss), 1e-12f);
  #pragma unroll
  for (int e = 0; e < 8; ++e) {
    const int c = c0 + e;
    const size_t idx = base + c;
    const float kk = kkr[e] * inv;
    const float a = 1.f / (1.f + expf(-(a0[c] + at[idx])));
    const float u = w0[c] + wt_decay[idx];
    const float sig_u = 1.f / (1.f + expf(-u));
    wt_decay[idx] = expf(-0.5488116360940264f * sig_u);
    const float kfin = kr[e] * fmaf(a - 1.f, k_a[c], 1.f);
    const float vr = v_buf[kvrow + kvoff + (c & 63)];
    const float sv = 1.f / (1.f + expf(-(v0[c] + vt_vf[idx])));
    vt_vf[idx] = vr + (v_first[idx] - vr) * sv;
    rk_pk[idx] = ((unsigned)f2b(kfin) << 16) | (unsigned)f2b(r_buf[idx]);
    ab_pk[idx] = ((unsigned)f2b(-kk) << 16) | (unsigned)f2b(kk * a);
  }
}

// ---------------------------------------------------------------------------
// RWKV-7 scan — cooperative-LDS, bf16-packed streams (round-2 structure).
//
// 512 blocks (2/CU, XCD-swizzled so all 4 blocks of a bh share one L2),
// 4 waves, 1 row/lane: wave (bh, quarter m, widx) rows m*16+4widx..+3; lane
// (rg,colg) holds S[row][4colg..+3]. Per step each wave reads LDS:
//   1 x b128 rk (u32: k|r bf16), 1 x b128 ab (aa|bb bf16), 1 x b128 d (f32),
//   1 x b32 v  -> ~42 cyc/wave/step vs round-2's 66 (5 f32 streams).
// 16-step chunks, double-buffered, counted vmcnt (STAGE=4 ops, YSTORE=1:
// WB(4) chunk0, WB(5) steady, WB(1) last). GroupNorm partials fused.
// ---------------------------------------------------------------------------
#define WB(n) asm volatile("s_waitcnt vmcnt(" #n ") lgkmcnt(0)\n\ts_barrier" ::: "memory")
#define BAR2() asm volatile("s_waitcnt lgkmcnt(0)\n\ts_barrier" ::: "memory")

__global__ __launch_bounds__(256) void scan_kernel(
    const unsigned* __restrict__ rkB, const unsigned* __restrict__ abB,
    const float* __restrict__ dB, const float* __restrict__ vB,
    const float* __restrict__ state, float* __restrict__ y,
    float* __restrict__ part)
{
  // LDS words: buf[p] at p*3328: rk[16][64] u32 at +0, ab at +1024,
  // d[16][64] f32 at +2048, v[16][16] f32 at +3072 (256). y at 6656 [16][16].
  // Total 6912 words = 27648 B.
  __shared__ float lds[6912];
  unsigned* ldsU = (unsigned*)lds;
  const int tid = threadIdx.x;
  const int bid = blockIdx.x;
  const int xcd = bid & 7, bj = bid >> 3;
  const int m = bj & 3, gq = bj >> 2;
  const int bh = (gq << 3) | xcd;
  const int widx = tid >> 6;
  const int lane = tid & 63;
  const int rg = lane >> 4;
  const int colg = lane & 15;
  const int rowb = (widx << 2) + rg;       // row within quarter, [0,16)
  const int row = (m << 4) + rowb;         // row within head, [0,64)
  const int b = bh >> 5, h = bh & 31;

  float4 S = *(const float4*)(state + (size_t)bh * 4096 + row * 64 + (colg << 2));

  const unsigned cb = (unsigned)((b * 1024) * 2048 + h * 64);
  const unsigned sstep = (unsigned)(tid >> 4);        // staging step 0..15
  const unsigned scol = (unsigned)((tid & 15) << 2);  // staging col 0,4,..,60
  const unsigned lseg = (unsigned)(widx << 8);        // 256 words per wave

  float sacc = 0.f, ssacc = 0.f;

  #define STAGE(step0, bofs) do {                                            \
    const unsigned go_ = cb + ((step0) + sstep) * 2048u + scol;              \
    async16(rkB + go_, ldsU + (bofs) + lseg);                                \
    async16(abB + go_, ldsU + (bofs) + 1024 + lseg);                         \
    async16(dB + go_,  lds + (bofs) + 2048 + lseg);                          \
    if (lane < 16) {                                                         \
      const unsigned gv_ = cb + ((step0) + (unsigned)(widx << 2)             \
                                 + (unsigned)(lane >> 2)) * 2048u            \
                           + (unsigned)(m << 4) + (unsigned)((lane & 3) << 2); \
      async16(vB + gv_, lds + (bofs) + 3072 + (widx << 6));                  \
    }                                                                        \
  } while (0)

  #define PROCESS(bofs) do {                                                 \
    _Pragma("unroll")                                                        \
    for (int s = 0; s < 16; ++s) {                                           \
      const uint4 rkw = *(const uint4*)(ldsU + (bofs) + s * 64 + (colg << 2)); \
      const uint4 abw = *(const uint4*)(ldsU + (bofs) + 1024 + s * 64 + (colg << 2)); \
      const float4 dv = *(const float4*)(lds + (bofs) + 2048 + s * 64 + (colg << 2)); \
      const float vv = lds[(bofs) + 3072 + (s << 4) + rowb];                 \
      const float aa0 = __uint_as_float(abw.x & 0xffff0000u);                \
      const float aa1 = __uint_as_float(abw.y & 0xffff0000u);                \
      const float aa2 = __uint_as_float(abw.z & 0xffff0000u);                \
      const float aa3 = __uint_as_float(abw.w & 0xffff0000u);                \
      const float bb0 = __uint_as_float(abw.x << 16);                        \
      const float bb1 = __uint_as_float(abw.y << 16);                        \
      const float bb2 = __uint_as_float(abw.z << 16);                        \
      const float bb3 = __uint_as_float(abw.w << 16);                        \
      const float k0 = __uint_as_float(rkw.x & 0xffff0000u);                 \
      const float k1 = __uint_as_float(rkw.y & 0xffff0000u);                 \
      const float k2 = __uint_as_float(rkw.z & 0xffff0000u);                 \
      const float k3 = __uint_as_float(rkw.w & 0xffff0000u);                 \
      const float r0 = __uint_as_float(rkw.x << 16);                         \
      const float r1 = __uint_as_float(rkw.y << 16);                         \
      const float r2 = __uint_as_float(rkw.z << 16);                         \
      const float r3 = __uint_as_float(rkw.w << 16);                         \
      float t0 = fmaf(S.y, aa1, S.x * aa0);                                  \
      t0 = fmaf(S.z, aa2, t0);                                               \
      t0 = fmaf(S.w, aa3, t0);                                               \
      const float sa = rowsum16(t0);                                         \
      S.x = fmaf(S.x, dv.x, fmaf(sa, bb0, vv * k0));                         \
      S.y = fmaf(S.y, dv.y, fmaf(sa, bb1, vv * k1));                         \
      S.z = fmaf(S.z, dv.z, fmaf(sa, bb2, vv * k2));                         \
      S.w = fmaf(S.w, dv.w, fmaf(sa, bb3, vv * k3));                         \
      float t1 = fmaf(S.y, r1, S.x * r0);                                    \
      t1 = fmaf(S.z, r2, t1);                                                \
      t1 = fmaf(S.w, r3, t1);                                                \
      const float yv = rowsum16(t1);                                         \
      if (colg == 0) {                                                       \
        lds[6656 + (s << 4) + rowb] = yv;                                    \
        sacc += yv;                                                          \
        ssacc = fmaf(yv, yv, ssacc);                                         \
      }                                                                      \
    }                                                                        \
  } while (0)

  #define YSTORE(step0) do {                                                 \
    const float val_ = lds[6656 + tid];                                      \
    y[cb + ((step0) + (unsigned)(tid >> 4)) * 2048u +                        \
      (unsigned)(m << 4) + (unsigned)(tid & 15)] = val_;                     \
  } while (0)

  STAGE(0u, 0);
  STAGE(16u, 3328);

  // chunk 0
  WB(4);
  PROCESS(0);
  BAR2();
  YSTORE(0u);
  STAGE(32u, 0);

  // chunks 1..62
  for (int c = 1; c <= 62; ++c) {
    const int bofs = (c & 1) ? 3328 : 0;
    WB(5);
    PROCESS(bofs);
    BAR2();
    YSTORE((unsigned)(c << 4));
    if (c < 62) STAGE((unsigned)((c + 2) << 4), bofs);
  }

  // chunk 63
  WB(1);
  PROCESS(3328);
  BAR2();
  YSTORE(1008u);

  // groupnorm partial for this (bh, quarter m): valid in colg==0 lanes.
  sacc  += __shfl_xor(sacc, 16);
  sacc  += __shfl_xor(sacc, 32);
  ssacc += __shfl_xor(ssacc, 16);
  ssacc += __shfl_xor(ssacc, 32);
  __syncthreads();
  if (lane == 0) { lds[widx] = sacc; lds[4 + widx] = ssacc; }
  __syncthreads();
  if (tid == 0) {
    const float s_  = lds[0] + lds[1] + lds[2] + lds[3];
    const float ss_ = lds[4] + lds[5] + lds[6] + lds[7];
    ((float2*)part)[(bh << 2) + m] = make_float2(s_, ss_);
  }

  #undef STAGE
  #undef PROCESS
  #undef YSTORE
}

// ---------------------------------------------------------------------------
// GroupNorm pass B + bonus: per-(b,t) row, writes xx in bf16.
// r,k for the bonus come from the packed rk stream (bf16).
// ---------------------------------------------------------------------------
__global__ __launch_bounds__(256) void gapply_kernel(
    const float* __restrict__ y, const unsigned* __restrict__ rkB,
    const float* __restrict__ vf,
    const float* __restrict__ part, const float* __restrict__ r_k,
    const float* __restrict__ ln_w, const float* __restrict__ ln_b,
    unsigned short* __restrict__ xxb)
{
  const int row = blockIdx.x;        // b*1024 + t
  const int b = row >> 10;
  const int tid = threadIdx.x;
  const int h = tid >> 3;
  const int bh = b * 32 + h;
  float s = 0.f, ss = 0.f;
  #pragma unroll
  for (int j = 0; j < 4; ++j) {
    const float2 pr = ((const float2*)part)[(bh << 2) + j];
    s += pr.x; ss += pr.y;
  }
  const float mean = s * (1.f / 65536.f);
  const float rstd = rsqrtf(ss * (1.f / 65536.f) - mean * mean + 0.00064f);
  const int c0 = tid << 3;
  const size_t base = (size_t)row * 2048 + c0;
  float yv[8], vv[8];
  float p = 0.f;
  #pragma unroll
  for (int e = 0; e < 8; ++e) {
    yv[e] = y[base + e];
    vv[e] = vf[base + e];
    const unsigned w_ = rkB[base + e];
    const float rr = __uint_as_float(w_ << 16);
    const float kk_ = __uint_as_float(w_ & 0xffff0000u);
    p = fmaf(rr * kk_, r_k[c0 + e], p);
  }
  p += __shfl_xor(p, 1);
  p += __shfl_xor(p, 2);
  p += __shfl_xor(p, 4);
  #pragma unroll
  for (int e = 0; e < 8; ++e) {
    const float yn = (yv[e] - mean) * rstd;
    xxb[base + e] = f2b(fmaf(yn, ln_w[c0 + e], ln_b[c0 + e]) + p * vv[e]);
  }
}

// ---------------------------------------------------------------------------
extern "C" void kernel_launch(void* const* d_in, const int* in_sizes, int n_in,
                              void* d_out, int out_size, void* d_ws, size_t ws_size,
                              hipStream_t stream) {
  const float* x       = (const float*)d_in[0];
  const float* v_first = (const float*)d_in[1];
  const float* state   = (const float*)d_in[2];
  const float* Rw      = (const float*)d_in[3];
  const float* R_bias  = (const float*)d_in[4];
  const float* Kw      = (const float*)d_in[5];
  const float* K_bias  = (const float*)d_in[6];
  const float* Vw      = (const float*)d_in[7];
  const float* V_bias  = (const float*)d_in[8];
  const float* Ow      = (const float*)d_in[9];
  const float* O_bias  = (const float*)d_in[10];
  const float* w0      = (const float*)d_in[11];
  const float* w1      = (const float*)d_in[12];
  const float* w2      = (const float*)d_in[13];
  const float* a0      = (const float*)d_in[14];
  const float* a1      = (const float*)d_in[15];
  const float* a2      = (const float*)d_in[16];
  const float* v0      = (const float*)d_in[17];
  const float* v1      = (const float*)d_in[18];
  const float* v2      = (const float*)d_in[19];
  const float* k_k     = (const float*)d_in[20];
  const float* k_a     = (const float*)d_in[21];
  const float* r_k     = (const float*)d_in[22];
  const float* ln_w    = (const float*)d_in[23];
  const float* ln_b    = (const float*)d_in[24];

  float* ws = (float*)d_ws;
  float* r_buf = ws;                    // 8388608
  float* k_buf = r_buf + 8388608;       // 2097152
  float* v_buf = k_buf + 2097152;       // 2097152
  float* wt    = v_buf + 2097152;       // 8388608 (u -> decay in place, f32)
  float* at    = wt    + 8388608;       // 8388608 (a pre-act -> y after scan)
  float* vt    = at    + 8388608;       // 8388608 (v pre-act -> v_final, f32)
  float* kf    = vt    + 8388608;       // 8388608 (bf16 weight aliases only)
  float* aaq   = kf    + 8388608;       // 8388608 -> rk_pk (u32)
  float* bbq   = aaq   + 8388608;       // 8388608 -> ab_pk (u32)
  float* part  = bbq   + 8388608;       // 2048 (gnorm partials)
  // bf16 aliases into dead-at-use regions (all 16B-aligned):
  unsigned short* xb   = (unsigned short*)bbq;               // dead before prep
  unsigned short* RKVb = (unsigned short*)kf;                // 3072x2048 bf16
  unsigned short* hcat = (unsigned short*)(kf + 3200000);    // 4096x160 bf16
  unsigned short* Bcat = (unsigned short*)(kf + 3600000);    // 160x2048 bf16
  unsigned short* w2t  = (unsigned short*)(kf + 3800000);    // 2048x64
  unsigned short* a2t  = (unsigned short*)(kf + 3900000);    // 2048x64
  unsigned short* v2t  = (unsigned short*)(kf + 4000000);    // 2048x32
  unsigned* rk_pk      = (unsigned*)aaq;                     // packed k|r bf16
  unsigned* ab_pk      = (unsigned*)bbq;                     // packed aa|bb bf16
  unsigned short* Ob   = (unsigned short*)wt;                // after scan
  unsigned short* xxb  = (unsigned short*)bbq;               // after scan

  dim3 blk(256);
  // ---- converts ----
  cvt4_kernel<<<14336, blk, 0, stream>>>(x, Rw, Kw, Vw, xb, RKVb);
  tcvt_all<<<192, blk, 0, stream>>>(w1, a1, v1, w2, a2, v2, Bcat, w2t, a2t, v2t);
  // ---- low-rank stage 1 (fused, bf16 out, tanh on w-cols) ----
  gemm_mfma<1,2><<<dim3(2, 32), blk, 0, stream>>>(xb, 2048, Bcat, 2048, nullptr,
                                                  hcat, 160, 4096, 160, 2048);
  // ---- merged R|K|V projection ----
  gemm_rkv<<<dim3(24, 32), blk, 0, stream>>>(xb, RKVb, R_bias, K_bias, V_bias,
                                             r_buf, k_buf, v_buf);
  // ---- low-rank stage 2 ----
  gemm_mfma<0,0><<<dim3(16, 32), blk, 0, stream>>>(hcat, 160, w2t, 64, nullptr,
                                                   wt, 2048, 4096, 2048, 64);
  gemm_mfma<0,0><<<dim3(16, 32), blk, 0, stream>>>(hcat + 64, 160, a2t, 64, nullptr,
                                                   at, 2048, 4096, 2048, 64);
  gemm_mfma<0,0><<<dim3(16, 32), blk, 0, stream>>>(hcat + 128, 160, v2t, 32, nullptr,
                                                   vt, 2048, 4096, 2048, 32);
  // ---- elementwise prep (writes packed bf16 streams) ----
  prep_kernel<<<4096, blk, 0, stream>>>(k_buf, v_buf, r_buf, wt, at, vt, v_first,
                                        w0, a0, v0, k_k, k_a, rk_pk, ab_pk);
  // ---- recurrent scan (bf16-packed streams; y reuses `at`) ----
  float* ybuf = at;
  scan_kernel<<<512, blk, 0, stream>>>(rk_pk, ab_pk, wt, vt, state, ybuf, part);
  // ---- O weight convert (wt dead after scan) ----
  cvt_bf16<<<4096, blk, 0, stream>>>(Ow, Ob, 1048576);
  // ---- group norm pass B + bonus -> bf16 xx (into bbq; ab_pk dead) ----
  gapply_kernel<<<4096, blk, 0, stream>>>(ybuf, rk_pk, vt, part, r_k,
                                          ln_w, ln_b, xxb);
  // ---- output projection ----
  gemm_mfma<0,0><<<dim3(16, 32), blk, 0, stream>>>(xxb, 2048, Ob, 2048, O_bias,
                                                   (float*)d_out, 2048, 4096, 2048, 2048);
}

// Round 5
// 748.389 us; speedup vs baseline: 1.1000x; 1.0229x over previous
//
#include <hip/hip_runtime.h>
#include <hip/hip_bf16.h>
#include <math.h>

typedef __attribute__((ext_vector_type(8))) short bf16x8;
typedef __attribute__((ext_vector_type(4))) float f32x4;

__device__ __forceinline__ unsigned short f2b(float f) {
  unsigned u = __float_as_uint(f);
  unsigned r = (u + 0x7FFF + ((u >> 16) & 1)) >> 16;
  return (unsigned short)r;
}

__device__ __forceinline__ void async16(const void* g, void* l) {
  __builtin_amdgcn_global_load_lds(
      (const __attribute__((address_space(1))) unsigned int*)(g),
      (__attribute__((address_space(3))) unsigned int*)(l), 16, 0, 0);
}

// Sum across the 16 lanes of a DPP row (lanes 16k..16k+15) via row_ror.
__device__ __forceinline__ float rowsum16(float x) {
  x += __int_as_float(__builtin_amdgcn_update_dpp(0, __float_as_int(x), 0x121, 0xF, 0xF, false));
  x += __int_as_float(__builtin_amdgcn_update_dpp(0, __float_as_int(x), 0x122, 0xF, 0xF, false));
  x += __int_as_float(__builtin_amdgcn_update_dpp(0, __float_as_int(x), 0x124, 0xF, 0xF, false));
  x += __int_as_float(__builtin_amdgcn_update_dpp(0, __float_as_int(x), 0x128, 0xF, 0xF, false));
  return x;
}

// v_fma_mix_f32: d = a(f32) * f16half(pk) + c(f32). No unpack instructions.
__device__ __forceinline__ float mixhi(float a, unsigned pk, float c) {
  float d;
  asm("v_fma_mix_f32 %0, %1, %2, %3 op_sel:[0,1,0] op_sel_hi:[0,1,0]"
      : "=v"(d) : "v"(a), "v"(pk), "v"(c));
  return d;
}
__device__ __forceinline__ float mixlo(float a, unsigned pk, float c) {
  float d;
  asm("v_fma_mix_f32 %0, %1, %2, %3 op_sel:[0,0,0] op_sel_hi:[0,1,0]"
      : "=v"(d) : "v"(a), "v"(pk), "v"(c));
  return d;
}
__device__ __forceinline__ float h2f(unsigned h) {
  float f; asm("v_cvt_f32_f16 %0, %1" : "=v"(f) : "v"(h)); return f;
}

// ---------------------------------------------------------------------------
// fp32 -> bf16 converts: x,R,K,V fused (R/K/V into one concatenated 3072x2048).
// ---------------------------------------------------------------------------
__global__ __launch_bounds__(256) void cvt4_kernel(
    const float* __restrict__ x, const float* __restrict__ R,
    const float* __restrict__ K, const float* __restrict__ V,
    unsigned short* __restrict__ xb, unsigned short* __restrict__ RKVb)
{
  const int bid = blockIdx.x;
  const float* s; unsigned short* d; int i;
  if (bid < 8192)       { s = x; d = xb; i = bid * 256 + threadIdx.x; }
  else if (bid < 12288) { s = R; d = RKVb; i = (bid - 8192) * 256 + threadIdx.x; }
  else if (bid < 13312) { s = K; d = RKVb + 2048 * 2048; i = (bid - 12288) * 256 + threadIdx.x; }
  else                  { s = V; d = RKVb + 2560 * 2048; i = (bid - 13312) * 256 + threadIdx.x; }
  float4 v = ((const float4*)s)[i];
  ushort4 o;
  o.x = f2b(v.x); o.y = f2b(v.y); o.z = f2b(v.z); o.w = f2b(v.w);
  ((ushort4*)d)[i] = o;
}

__global__ __launch_bounds__(256) void cvt_bf16(
    const float* __restrict__ s, unsigned short* __restrict__ d, int n4)
{
  int i = blockIdx.x * 256 + threadIdx.x;
  if (i < n4) {
    float4 v = ((const float4*)s)[i];
    ushort4 o;
    o.x = f2b(v.x); o.y = f2b(v.y); o.z = f2b(v.z); o.w = f2b(v.w);
    ((ushort4*)d)[i] = o;
  }
}

// ---------------------------------------------------------------------------
// Transposed converts, all 6 small matrices in ONE launch (192 blocks):
// out[n*ors + k] = bf16(in[k*Nd + n]).
// ---------------------------------------------------------------------------
__global__ __launch_bounds__(256) void tcvt_all(
    const float* __restrict__ w1, const float* __restrict__ a1,
    const float* __restrict__ v1, const float* __restrict__ w2,
    const float* __restrict__ a2, const float* __restrict__ v2,
    unsigned short* __restrict__ Bcat, unsigned short* __restrict__ w2t,
    unsigned short* __restrict__ a2t, unsigned short* __restrict__ v2t)
{
  const int r = blockIdx.x >> 5, i = blockIdx.x & 31;
  const float* in; unsigned short* out; int Kd, Nd, ors, bx, by;
  switch (r) {
    case 0:  in = w1; out = Bcat;             Kd = 2048; Nd = 64;   ors = 2048; bx = 0; by = i; break;
    case 1:  in = a1; out = Bcat + 64 * 2048; Kd = 2048; Nd = 64;   ors = 2048; bx = 0; by = i; break;
    case 2:  in = v1; out = Bcat + 128 * 2048; Kd = 2048; Nd = 32;  ors = 2048; bx = 0; by = i; break;
    case 3:  in = w2; out = w2t;              Kd = 64;   Nd = 2048; ors = 64;   bx = i; by = 0; break;
    case 4:  in = a2; out = a2t;              Kd = 64;   Nd = 2048; ors = 64;   bx = i; by = 0; break;
    default: in = v2; out = v2t;              Kd = 32;   Nd = 2048; ors = 32;   bx = i; by = 0; break;
  }
  __shared__ unsigned short tile[64][65];
  const int tx = threadIdx.x & 63, ty = threadIdx.x >> 6;
  const int n0 = bx * 64, k0 = by * 64;
  #pragma unroll
  for (int j = 0; j < 16; ++j) {
    const int k = k0 + j * 4 + ty;
    const int n = n0 + tx;
    unsigned short v = 0;
    if (k < Kd && n < Nd) v = f2b(in[(size_t)k * Nd + n]);
    tile[j * 4 + ty][tx] = v;
  }
  __syncthreads();
  #pragma unroll
  for (int j = 0; j < 16; ++j) {
    const int n = n0 + j * 4 + ty;
    const int k = k0 + tx;
    if (n < Nd && k < Kd) out[(size_t)n * ors + k] = tile[tx][j * 4 + ty];
  }
}

// ---------------------------------------------------------------------------
// bf16 MFMA GEMM body: C[M,N] = A[M,K] @ B[N,K]^T (+bias). 128x128 tile, BK=32.
// ---------------------------------------------------------------------------
template<int OUTBF16, int ACT>
__device__ __forceinline__ void gemm_body(
    const unsigned short* __restrict__ A, int lda,
    const unsigned short* __restrict__ B, int ldb,
    const float* __restrict__ bias, void* __restrict__ Cv, int ldc,
    int M, int N, int K, int row0, int col0)
{
  __shared__ __align__(16) unsigned short As[128 * 32];
  __shared__ __align__(16) unsigned short Bs[128 * 32];
  const int tid = threadIdx.x;
  const int w = tid >> 6, lane = tid & 63;
  const int wr = (w >> 1) * 64, wc = (w & 1) * 64;

  f32x4 acc[4][4];
  #pragma unroll
  for (int i = 0; i < 4; ++i)
    #pragma unroll
    for (int j = 0; j < 4; ++j)
      acc[i][j] = (f32x4){0.f, 0.f, 0.f, 0.f};

  const int srow = w * 32 + (lane >> 2);
  const int scol = (lane & 3) * 8;
  const int brow0 = (col0 + srow < N) ? (col0 + srow) : 0;
  const int brow1 = (col0 + srow + 16 < N) ? (col0 + srow + 16) : 0;
  const unsigned short* gA0 = A + (size_t)(row0 + srow) * lda + scol;
  const unsigned short* gA1 = gA0 + (size_t)16 * lda;
  const unsigned short* gB0 = B + (size_t)brow0 * ldb + scol;
  const unsigned short* gB1 = B + (size_t)brow1 * ldb + scol;
  unsigned short* lA0 = As + w * 1024;
  unsigned short* lA1 = As + w * 1024 + 512;
  unsigned short* lB0 = Bs + w * 1024;
  unsigned short* lB1 = Bs + w * 1024 + 512;

  const int m16 = lane & 15;
  const int q8  = (lane >> 4) * 8;

  for (int k0 = 0; k0 < K; k0 += 32) {
    async16(gA0, lA0);
    async16(gA1, lA1);
    async16(gB0, lB0);
    async16(gB1, lB1);
    gA0 += 32; gA1 += 32; gB0 += 32; gB1 += 32;
    __syncthreads();
    bf16x8 af[4], bfr[4];
    #pragma unroll
    for (int i = 0; i < 4; ++i) {
      af[i]  = *(const bf16x8*)(As + (wr + i * 16 + m16) * 32 + q8);
      bfr[i] = *(const bf16x8*)(Bs + (wc + i * 16 + m16) * 32 + q8);
    }
    #pragma unroll
    for (int i = 0; i < 4; ++i)
      #pragma unroll
      for (int j = 0; j < 4; ++j)
        acc[i][j] = __builtin_amdgcn_mfma_f32_16x16x32_bf16(af[i], bfr[j], acc[i][j], 0, 0, 0);
    __syncthreads();
  }

  #pragma unroll
  for (int j = 0; j < 4; ++j) {
    const int c_ = col0 + wc + j * 16 + (lane & 15);
    if (c_ < N) {
      const float bv = bias ? bias[c_] : 0.f;
      #pragma unroll
      for (int i = 0; i < 4; ++i) {
        const int r_ = row0 + wr + i * 16 + (lane >> 4) * 4;
        #pragma unroll
        for (int t4 = 0; t4 < 4; ++t4) {
          float v = acc[i][j][t4] + bv;
          if (ACT == 2 && c_ < 64) v = tanhf(v);
          if (OUTBF16)
            ((unsigned short*)Cv)[(size_t)(r_ + t4) * ldc + c_] = f2b(v);
          else
            ((float*)Cv)[(size_t)(r_ + t4) * ldc + c_] = v;
        }
      }
    }
  }
}

template<int OUTBF16, int ACT>
__global__ __launch_bounds__(256) void gemm_mfma(
    const unsigned short* __restrict__ A, int lda,
    const unsigned short* __restrict__ B, int ldb,
    const float* __restrict__ bias, void* __restrict__ Cv, int ldc,
    int M, int N, int K)
{
  gemm_body<OUTBF16, ACT>(A, lda, B, ldb, bias, Cv, ldc, M, N, K,
                          blockIdx.y * 128, blockIdx.x * 128);
}

// Merged low-rank stage-2: blockIdx.z selects (w | a | v) region.
__global__ __launch_bounds__(256) void gemm_lr2(
    const unsigned short* __restrict__ hcat,
    const unsigned short* __restrict__ w2t,
    const unsigned short* __restrict__ a2t,
    const unsigned short* __restrict__ v2t,
    float* __restrict__ wt, float* __restrict__ at, float* __restrict__ vt)
{
  const int z = blockIdx.z;
  const unsigned short* A; const unsigned short* Bm; float* C; int K;
  if (z == 0)      { A = hcat;       Bm = w2t; C = wt; K = 64; }
  else if (z == 1) { A = hcat + 64;  Bm = a2t; C = at; K = 64; }
  else             { A = hcat + 128; Bm = v2t; C = vt; K = 32; }
  gemm_body<0, 0>(A, 160, Bm, K, nullptr, C, 2048, 4096, 2048, K,
                  blockIdx.y * 128, blockIdx.x * 128);
}

// ---------------------------------------------------------------------------
// Merged R|K|V projection GEMM: B is the concatenated (3072 x 2048) weight.
// ---------------------------------------------------------------------------
__global__ __launch_bounds__(256) void gemm_rkv(
    const unsigned short* __restrict__ A, const unsigned short* __restrict__ B,
    const float* __restrict__ Rb_, const float* __restrict__ Kb_,
    const float* __restrict__ Vb_,
    float* __restrict__ Cr, float* __restrict__ Ck, float* __restrict__ Cvv)
{
  const int col0 = blockIdx.x * 128;
  float* Cd; int ldc, cbase; const float* bias;
  if (col0 < 2048)      { Cd = Cr;  ldc = 2048; cbase = col0;        bias = Rb_; }
  else if (col0 < 2560) { Cd = Ck;  ldc = 512;  cbase = col0 - 2048; bias = Kb_; }
  else                  { Cd = Cvv; ldc = 512;  cbase = col0 - 2560; bias = Vb_; }
  // N passed as 3072 but col0 region-local: use body with col0 remapped.
  __shared__ __align__(16) unsigned short As[128 * 32];
  __shared__ __align__(16) unsigned short Bs[128 * 32];
  const int tid = threadIdx.x;
  const int w = tid >> 6, lane = tid & 63;
  const int wr = (w >> 1) * 64, wc = (w & 1) * 64;
  const int row0 = blockIdx.y * 128;

  f32x4 acc[4][4];
  #pragma unroll
  for (int i = 0; i < 4; ++i)
    #pragma unroll
    for (int j = 0; j < 4; ++j)
      acc[i][j] = (f32x4){0.f, 0.f, 0.f, 0.f};

  const int srow = w * 32 + (lane >> 2);
  const int scol = (lane & 3) * 8;
  const unsigned short* gA0 = A + (size_t)(row0 + srow) * 2048 + scol;
  const unsigned short* gA1 = gA0 + (size_t)16 * 2048;
  const unsigned short* gB0 = B + (size_t)(col0 + srow) * 2048 + scol;
  const unsigned short* gB1 = gB0 + (size_t)16 * 2048;
  unsigned short* lA0 = As + w * 1024;
  unsigned short* lA1 = As + w * 1024 + 512;
  unsigned short* lB0 = Bs + w * 1024;
  unsigned short* lB1 = Bs + w * 1024 + 512;

  const int m16 = lane & 15;
  const int q8  = (lane >> 4) * 8;

  for (int k0 = 0; k0 < 2048; k0 += 32) {
    async16(gA0, lA0);
    async16(gA1, lA1);
    async16(gB0, lB0);
    async16(gB1, lB1);
    gA0 += 32; gA1 += 32; gB0 += 32; gB1 += 32;
    __syncthreads();
    bf16x8 af[4], bfr[4];
    #pragma unroll
    for (int i = 0; i < 4; ++i) {
      af[i]  = *(const bf16x8*)(As + (wr + i * 16 + m16) * 32 + q8);
      bfr[i] = *(const bf16x8*)(Bs + (wc + i * 16 + m16) * 32 + q8);
    }
    #pragma unroll
    for (int i = 0; i < 4; ++i)
      #pragma unroll
      for (int j = 0; j < 4; ++j)
        acc[i][j] = __builtin_amdgcn_mfma_f32_16x16x32_bf16(af[i], bfr[j], acc[i][j], 0, 0, 0);
    __syncthreads();
  }

  #pragma unroll
  for (int j = 0; j < 4; ++j) {
    const int c_ = cbase + wc + j * 16 + (lane & 15);
    const float bv = bias[c_];
    #pragma unroll
    for (int i = 0; i < 4; ++i) {
      const int r_ = row0 + wr + i * 16 + (lane >> 4) * 4;
      #pragma unroll
      for (int t4 = 0; t4 < 4; ++t4)
        Cd[(size_t)(r_ + t4) * ldc + c_] = acc[i][j][t4] + bv;
    }
  }
}

// ---------------------------------------------------------------------------
// Elementwise prep. Packs scan streams as f16 pairs (v_cvt_pkrtz):
//   rk_pk[idx] = [hi=f16(k_final) | lo=f16(r)]
//   ab_pk[idx] = [hi=f16(aa)      | lo=f16(bb)]
// f16 (10-bit mantissa) beats the bf16 used in round 4. decay (wt) and
// v_final (vt) stay f32 (decay compounds multiplicatively over 1024 steps).
// ---------------------------------------------------------------------------
__global__ __launch_bounds__(256) void prep_kernel(
    const float* __restrict__ k_buf, const float* __restrict__ v_buf,
    const float* __restrict__ r_buf,
    float* wt_decay, const float* __restrict__ at, float* vt_vf,
    const float* __restrict__ v_first,
    const float* __restrict__ w0, const float* __restrict__ a0,
    const float* __restrict__ v0, const float* __restrict__ k_k,
    const float* __restrict__ k_a,
    unsigned* __restrict__ rk_pk, unsigned* __restrict__ ab_pk)
{
  const int row = blockIdx.x;
  const int tid = threadIdx.x;
  const int c0 = tid << 3;
  const int h = tid >> 3;
  const int kvoff = (h >> 2) << 6;
  const size_t base = (size_t)row * 2048;
  const size_t kvrow = (size_t)row * 512;
  float kr[8], kkr[8];
  float ss = 0.f;
  #pragma unroll
  for (int e = 0; e < 8; ++e) {
    const int c = c0 + e;
    const float kv = k_buf[kvrow + kvoff + (c & 63)];
    kr[e] = kv;
    const float t = kv * k_k[c];
    kkr[e] = t;
    ss = fmaf(t, t, ss);
  }
  ss += __shfl_xor(ss, 1);
  ss += __shfl_xor(ss, 2);
  ss += __shfl_xor(ss, 4);
  const float inv = 1.f / fmaxf(sqrtf(ss), 1e-12f);
  #pragma unroll
  for (int e = 0; e < 8; ++e) {
    const int c = c0 + e;
    const size_t idx = base + c;
    const float kk = kkr[e] * inv;
    const float a = 1.f / (1.f + expf(-(a0[c] + at[idx])));
    const float u = w0[c] + wt_decay[idx];
    const float sig_u = 1.f / (1.f + expf(-u));
    wt_decay[idx] = expf(-0.5488116360940264f * sig_u);
    const float kfin = kr[e] * fmaf(a - 1.f, k_a[c], 1.f);
    const float vr = v_buf[kvrow + kvoff + (c & 63)];
    const float sv = 1.f / (1.f + expf(-(v0[c] + vt_vf[idx])));
    vt_vf[idx] = vr + (v_first[idx] - vr) * sv;
    const float bbv = kk * a;
    const float aav = -kk;
    unsigned rk_u, ab_u;
    asm("v_cvt_pkrtz_f16_f32 %0, %1, %2" : "=v"(rk_u) : "v"(r_buf[idx]), "v"(kfin));
    asm("v_cvt_pkrtz_f16_f32 %0, %1, %2" : "=v"(ab_u) : "v"(bbv), "v"(aav));
    rk_pk[idx] = rk_u;
    ab_pk[idx] = ab_u;
  }
}

// ---------------------------------------------------------------------------
// RWKV-7 scan — cooperative-LDS, f16-packed streams + v_fma_mix (no unpack).
//
// 512 blocks (2/CU, XCD-swizzled), 4 waves, 1 row/lane. Per step per wave:
// 3 x ds_read_b128 (rk, ab, d) + 1 x ds_read_b32 (v); VALU ~31 ops/step
// (was 48 with bf16 bit-unpack): f16 stream operands are consumed directly
// by v_fma_mix_f32 op_sel halves. Same chunk/dbuf/vmcnt skeleton as the
// passing round-4 kernel: WB(4) chunk0, WB(5) steady, WB(1) last.
// GroupNorm partials fused.
// ---------------------------------------------------------------------------
#define WB(n) asm volatile("s_waitcnt vmcnt(" #n ") lgkmcnt(0)\n\ts_barrier" ::: "memory")
#define BAR2() asm volatile("s_waitcnt lgkmcnt(0)\n\ts_barrier" ::: "memory")

__global__ __launch_bounds__(256) void scan_kernel(
    const unsigned* __restrict__ rkB, const unsigned* __restrict__ abB,
    const float* __restrict__ dB, const float* __restrict__ vB,
    const float* __restrict__ state, float* __restrict__ y,
    float* __restrict__ part)
{
  // LDS words: buf[p] at p*3328: rk[16][64] u32 at +0, ab at +1024,
  // d[16][64] f32 at +2048, v[16][16] f32 at +3072 (256). y at 6656 [16][16].
  // Total 6912 words = 27648 B.
  __shared__ float lds[6912];
  unsigned* ldsU = (unsigned*)lds;
  const int tid = threadIdx.x;
  const int bid = blockIdx.x;
  const int xcd = bid & 7, bj = bid >> 3;
  const int m = bj & 3, gq = bj >> 2;
  const int bh = (gq << 3) | xcd;
  const int widx = tid >> 6;
  const int lane = tid & 63;
  const int rg = lane >> 4;
  const int colg = lane & 15;
  const int rowb = (widx << 2) + rg;       // row within quarter, [0,16)
  const int row = (m << 4) + rowb;         // row within head, [0,64)
  const int b = bh >> 5, h = bh & 31;

  float4 S = *(const float4*)(state + (size_t)bh * 4096 + row * 64 + (colg << 2));

  const unsigned cb = (unsigned)((b * 1024) * 2048 + h * 64);
  const unsigned sstep = (unsigned)(tid >> 4);        // staging step 0..15
  const unsigned scol = (unsigned)((tid & 15) << 2);  // staging col 0,4,..,60
  const unsigned lseg = (unsigned)(widx << 8);        // 256 words per wave

  float sacc = 0.f, ssacc = 0.f;
  const float fzero = 0.0f;

  #define STAGE(step0, bofs) do {                                            \
    const unsigned go_ = cb + ((step0) + sstep) * 2048u + scol;              \
    async16(rkB + go_, ldsU + (bofs) + lseg);                                \
    async16(abB + go_, ldsU + (bofs) + 1024 + lseg);                         \
    async16(dB + go_,  lds + (bofs) + 2048 + lseg);                          \
    if (lane < 16) {                                                         \
      const unsigned gv_ = cb + ((step0) + (unsigned)(widx << 2)             \
                                 + (unsigned)(lane >> 2)) * 2048u            \
                           + (unsigned)(m << 4) + (unsigned)((lane & 3) << 2); \
      async16(vB + gv_, lds + (bofs) + 3072 + (widx << 6));                  \
    }                                                                        \
  } while (0)

  #define PROCESS(bofs) do {                                                 \
    _Pragma("unroll")                                                        \
    for (int s = 0; s < 16; ++s) {                                           \
      const uint4 rkw = *(const uint4*)(ldsU + (bofs) + s * 64 + (colg << 2)); \
      const uint4 abw = *(const uint4*)(ldsU + (bofs) + 1024 + s * 64 + (colg << 2)); \
      const float4 dv = *(const float4*)(lds + (bofs) + 2048 + s * 64 + (colg << 2)); \
      const float vv = lds[(bofs) + 3072 + (s << 4) + rowb];                 \
      float t0 = mixhi(S.x, abw.x, fzero);                                   \
      t0 = mixhi(S.y, abw.y, t0);                                            \
      t0 = mixhi(S.z, abw.z, t0);                                            \
      t0 = mixhi(S.w, abw.w, t0);                                            \
      const float sa = rowsum16(t0);                                         \
      float p0 = mixhi(vv, rkw.x, fzero);                                    \
      float p1 = mixhi(vv, rkw.y, fzero);                                    \
      float p2 = mixhi(vv, rkw.z, fzero);                                    \
      float p3 = mixhi(vv, rkw.w, fzero);                                    \
      p0 = mixlo(sa, abw.x, p0);                                             \
      p1 = mixlo(sa, abw.y, p1);                                             \
      p2 = mixlo(sa, abw.z, p2);                                             \
      p3 = mixlo(sa, abw.w, p3);                                             \
      S.x = fmaf(S.x, dv.x, p0);                                             \
      S.y = fmaf(S.y, dv.y, p1);                                             \
      S.z = fmaf(S.z, dv.z, p2);                                             \
      S.w = fmaf(S.w, dv.w, p3);                                             \
      float t1 = mixlo(S.x, rkw.x, fzero);                                   \
      t1 = mixlo(S.y, rkw.y, t1);                                            \
      t1 = mixlo(S.z, rkw.z, t1);                                            \
      t1 = mixlo(S.w, rkw.w, t1);                                            \
      const float yv = rowsum16(t1);                                         \
      if (colg == 0) {                                                       \
        lds[6656 + (s << 4) + rowb] = yv;                                    \
        sacc += yv;                                                          \
        ssacc = fmaf(yv, yv, ssacc);                                         \
      }                                                                      \
    }                                                                        \
  } while (0)

  #define YSTORE(step0) do {                                                 \
    const float val_ = lds[6656 + tid];                                      \
    y[cb + ((step0) + (unsigned)(tid >> 4)) * 2048u +                        \
      (unsigned)(m << 4) + (unsigned)(tid & 15)] = val_;                     \
  } while (0)

  STAGE(0u, 0);
  STAGE(16u, 3328);

  // chunk 0
  WB(4);
  PROCESS(0);
  BAR2();
  YSTORE(0u);
  STAGE(32u, 0);

  // chunks 1..62
  for (int c = 1; c <= 62; ++c) {
    const int bofs = (c & 1) ? 3328 : 0;
    WB(5);
    PROCESS(bofs);
    BAR2();
    YSTORE((unsigned)(c << 4));
    if (c < 62) STAGE((unsigned)((c + 2) << 4), bofs);
  }

  // chunk 63
  WB(1);
  PROCESS(3328);
  BAR2();
  YSTORE(1008u);

  // groupnorm partial for this (bh, quarter m): valid in colg==0 lanes.
  sacc  += __shfl_xor(sacc, 16);
  sacc  += __shfl_xor(sacc, 32);
  ssacc += __shfl_xor(ssacc, 16);
  ssacc += __shfl_xor(ssacc, 32);
  __syncthreads();
  if (lane == 0) { lds[widx] = sacc; lds[4 + widx] = ssacc; }
  __syncthreads();
  if (tid == 0) {
    const float s_  = lds[0] + lds[1] + lds[2] + lds[3];
    const float ss_ = lds[4] + lds[5] + lds[6] + lds[7];
    ((float2*)part)[(bh << 2) + m] = make_float2(s_, ss_);
  }

  #undef STAGE
  #undef PROCESS
  #undef YSTORE
}

// ---------------------------------------------------------------------------
// GroupNorm pass B + bonus: per-(b,t) row, writes xx in bf16.
// r,k for the bonus come from the packed f16 rk stream.
// ---------------------------------------------------------------------------
__global__ __launch_bounds__(256) void gapply_kernel(
    const float* __restrict__ y, const unsigned* __restrict__ rkB,
    const float* __restrict__ vf,
    const float* __restrict__ part, const float* __restrict__ r_k,
    const float* __restrict__ ln_w, const float* __restrict__ ln_b,
    unsigned short* __restrict__ xxb)
{
  const int row = blockIdx.x;        // b*1024 + t
  const int b = row >> 10;
  const int tid = threadIdx.x;
  const int h = tid >> 3;
  const int bh = b * 32 + h;
  float s = 0.f, ss = 0.f;
  #pragma unroll
  for (int j = 0; j < 4; ++j) {
    const float2 pr = ((const float2*)part)[(bh << 2) + j];
    s += pr.x; ss += pr.y;
  }
  const float mean = s * (1.f / 65536.f);
  const float rstd = rsqrtf(ss * (1.f / 65536.f) - mean * mean + 0.00064f);
  const int c0 = tid << 3;
  const size_t base = (size_t)row * 2048 + c0;
  float yv[8], vv[8];
  float p = 0.f;
  #pragma unroll
  for (int e = 0; e < 8; ++e) {
    yv[e] = y[base + e];
    vv[e] = vf[base + e];
    const unsigned w_ = rkB[base + e];
    p = fmaf(h2f(w_ & 0xffffu) * h2f(w_ >> 16), r_k[c0 + e], p);
  }
  p += __shfl_xor(p, 1);
  p += __shfl_xor(p, 2);
  p += __shfl_xor(p, 4);
  #pragma unroll
  for (int e = 0; e < 8; ++e) {
    const float yn = (yv[e] - mean) * rstd;
    xxb[base + e] = f2b(fmaf(yn, ln_w[c0 + e], ln_b[c0 + e]) + p * vv[e]);
  }
}

// ---------------------------------------------------------------------------
extern "C" void kernel_launch(void* const* d_in, const int* in_sizes, int n_in,
                              void* d_out, int out_size, void* d_ws, size_t ws_size,
                              hipStream_t stream) {
  const float* x       = (const float*)d_in[0];
  const float* v_first = (const float*)d_in[1];
  const float* state   = (const float*)d_in[2];
  const float* Rw      = (const float*)d_in[3];
  const float* R_bias  = (const float*)d_in[4];
  const float* Kw      = (const float*)d_in[5];
  const float* K_bias  = (const float*)d_in[6];
  const float* Vw      = (const float*)d_in[7];
  const float* V_bias  = (const float*)d_in[8];
  const float* Ow      = (const float*)d_in[9];
  const float* O_bias  = (const float*)d_in[10];
  const float* w0      = (const float*)d_in[11];
  const float* w1      = (const float*)d_in[12];
  const float* w2      = (const float*)d_in[13];
  const float* a0      = (const float*)d_in[14];
  const float* a1      = (const float*)d_in[15];
  const float* a2      = (const float*)d_in[16];
  const float* v0      = (const float*)d_in[17];
  const float* v1      = (const float*)d_in[18];
  const float* v2      = (const float*)d_in[19];
  const float* k_k     = (const float*)d_in[20];
  const float* k_a     = (const float*)d_in[21];
  const float* r_k     = (const float*)d_in[22];
  const float* ln_w    = (const float*)d_in[23];
  const float* ln_b    = (const float*)d_in[24];

  float* ws = (float*)d_ws;
  float* r_buf = ws;                    // 8388608
  float* k_buf = r_buf + 8388608;       // 2097152
  float* v_buf = k_buf + 2097152;       // 2097152
  float* wt    = v_buf + 2097152;       // 8388608 (u -> decay in place, f32)
  float* at    = wt    + 8388608;       // 8388608 (a pre-act -> y after scan)
  float* vt    = at    + 8388608;       // 8388608 (v pre-act -> v_final, f32)
  float* kf    = vt    + 8388608;       // 8388608 (bf16 weight aliases only)
  float* aaq   = kf    + 8388608;       // 8388608 -> rk_pk (u32)
  float* bbq   = aaq   + 8388608;       // 8388608 -> ab_pk (u32)
  float* part  = bbq   + 8388608;       // 2048 (gnorm partials)
  // bf16 aliases into dead-at-use regions (all 16B-aligned):
  unsigned short* xb   = (unsigned short*)bbq;               // dead before prep
  unsigned short* RKVb = (unsigned short*)kf;                // 3072x2048 bf16
  unsigned short* hcat = (unsigned short*)(kf + 3200000);    // 4096x160 bf16
  unsigned short* Bcat = (unsigned short*)(kf + 3600000);    // 160x2048 bf16
  unsigned short* w2t  = (unsigned short*)(kf + 3800000);    // 2048x64
  unsigned short* a2t  = (unsigned short*)(kf + 3900000);    // 2048x64
  unsigned short* v2t  = (unsigned short*)(kf + 4000000);    // 2048x32
  unsigned* rk_pk      = (unsigned*)aaq;                     // packed f16 k|r
  unsigned* ab_pk      = (unsigned*)bbq;                     // packed f16 aa|bb
  unsigned short* Ob   = (unsigned short*)wt;                // after scan
  unsigned short* xxb  = (unsigned short*)bbq;               // after scan

  dim3 blk(256);
  // ---- converts ----
  cvt4_kernel<<<14336, blk, 0, stream>>>(x, Rw, Kw, Vw, xb, RKVb);
  tcvt_all<<<192, blk, 0, stream>>>(w1, a1, v1, w2, a2, v2, Bcat, w2t, a2t, v2t);
  // ---- low-rank stage 1 (fused, bf16 out, tanh on w-cols) ----
  gemm_mfma<1,2><<<dim3(2, 32), blk, 0, stream>>>(xb, 2048, Bcat, 2048, nullptr,
                                                  hcat, 160, 4096, 160, 2048);
  // ---- merged R|K|V projection ----
  gemm_rkv<<<dim3(24, 32), blk, 0, stream>>>(xb, RKVb, R_bias, K_bias, V_bias,
                                             r_buf, k_buf, v_buf);
  // ---- low-rank stage 2 (w|a|v merged into one launch) ----
  gemm_lr2<<<dim3(16, 32, 3), blk, 0, stream>>>(hcat, w2t, a2t, v2t, wt, at, vt);
  // ---- elementwise prep (writes packed f16 streams) ----
  prep_kernel<<<4096, blk, 0, stream>>>(k_buf, v_buf, r_buf, wt, at, vt, v_first,
                                        w0, a0, v0, k_k, k_a, rk_pk, ab_pk);
  // ---- recurrent scan (f16-packed streams + fma_mix; y reuses `at`) ----
  float* ybuf = at;
  scan_kernel<<<512, blk, 0, stream>>>(rk_pk, ab_pk, wt, vt, state, ybuf, part);
  // ---- O weight convert (wt dead after scan) ----
  cvt_bf16<<<4096, blk, 0, stream>>>(Ow, Ob, 1048576);
  // ---- group norm pass B + bonus -> bf16 xx (into bbq; ab_pk dead) ----
  gapply_kernel<<<4096, blk, 0, stream>>>(ybuf, rk_pk, vt, part, r_k,
                                          ln_w, ln_b, xxb);
  // ---- output projection ----
  gemm_mfma<0,0><<<dim3(16, 32), blk, 0, stream>>>(xxb, 2048, Ob, 2048, O_bias,
                                                   (float*)d_out, 2048, 4096, 2048, 2048);
}

// Round 6
// 735.713 us; speedup vs baseline: 1.1189x; 1.0172x over previous
//
#include <hip/hip_runtime.h>
#include <hip/hip_bf16.h>
#include <math.h>

typedef __attribute__((ext_vector_type(8))) short bf16x8;
typedef __attribute__((ext_vector_type(4))) float f32x4;

__device__ __forceinline__ unsigned short f2b(float f) {
  unsigned u = __float_as_uint(f);
  unsigned r = (u + 0x7FFF + ((u >> 16) & 1)) >> 16;
  return (unsigned short)r;
}

__device__ __forceinline__ void async16(const void* g, void* l) {
  __builtin_amdgcn_global_load_lds(
      (const __attribute__((address_space(1))) unsigned int*)(g),
      (__attribute__((address_space(3))) unsigned int*)(l), 16, 0, 0);
}

// Sum across the 16 lanes of a DPP row (lanes 16k..16k+15) via row_ror.
__device__ __forceinline__ float rowsum16(float x) {
  x += __int_as_float(__builtin_amdgcn_update_dpp(0, __float_as_int(x), 0x121, 0xF, 0xF, false));
  x += __int_as_float(__builtin_amdgcn_update_dpp(0, __float_as_int(x), 0x122, 0xF, 0xF, false));
  x += __int_as_float(__builtin_amdgcn_update_dpp(0, __float_as_int(x), 0x124, 0xF, 0xF, false));
  x += __int_as_float(__builtin_amdgcn_update_dpp(0, __float_as_int(x), 0x128, 0xF, 0xF, false));
  return x;
}

// v_fma_mix_f32: d = a(f32) * f16half(pk) + c(f32). No unpack instructions.
__device__ __forceinline__ float mixhi(float a, unsigned pk, float c) {
  float d;
  asm("v_fma_mix_f32 %0, %1, %2, %3 op_sel:[0,1,0] op_sel_hi:[0,1,0]"
      : "=v"(d) : "v"(a), "v"(pk), "v"(c));
  return d;
}
__device__ __forceinline__ float mixlo(float a, unsigned pk, float c) {
  float d;
  asm("v_fma_mix_f32 %0, %1, %2, %3 op_sel:[0,0,0] op_sel_hi:[0,1,0]"
      : "=v"(d) : "v"(a), "v"(pk), "v"(c));
  return d;
}
__device__ __forceinline__ float h2f(unsigned h) {
  float f; asm("v_cvt_f32_f16 %0, %1" : "=v"(f) : "v"(h)); return f;
}

// ---------------------------------------------------------------------------
// fp32 -> bf16 converts: x, R|K|V (concatenated 3072x2048) AND Ow, all in one
// launch. Ob lives in the dead tail of the kf region so it can be written
// here at the start (deletes the separate cvt launch).
// ---------------------------------------------------------------------------
__global__ __launch_bounds__(256) void cvt4_kernel(
    const float* __restrict__ x, const float* __restrict__ R,
    const float* __restrict__ K, const float* __restrict__ V,
    const float* __restrict__ Ow,
    unsigned short* __restrict__ xb, unsigned short* __restrict__ RKVb,
    unsigned short* __restrict__ Ob)
{
  const int bid = blockIdx.x;
  const float* s; unsigned short* d; int i;
  if (bid < 8192)       { s = x; d = xb; i = bid * 256 + threadIdx.x; }
  else if (bid < 12288) { s = R; d = RKVb; i = (bid - 8192) * 256 + threadIdx.x; }
  else if (bid < 13312) { s = K; d = RKVb + 2048 * 2048; i = (bid - 12288) * 256 + threadIdx.x; }
  else if (bid < 14336) { s = V; d = RKVb + 2560 * 2048; i = (bid - 13312) * 256 + threadIdx.x; }
  else                  { s = Ow; d = Ob; i = (bid - 14336) * 256 + threadIdx.x; }
  float4 v = ((const float4*)s)[i];
  ushort4 o;
  o.x = f2b(v.x); o.y = f2b(v.y); o.z = f2b(v.z); o.w = f2b(v.w);
  ((ushort4*)d)[i] = o;
}

// ---------------------------------------------------------------------------
// Transposed converts, all 6 small matrices in ONE launch (192 blocks):
// out[n*ors + k] = bf16(in[k*Nd + n]).
// ---------------------------------------------------------------------------
__global__ __launch_bounds__(256) void tcvt_all(
    const float* __restrict__ w1, const float* __restrict__ a1,
    const float* __restrict__ v1, const float* __restrict__ w2,
    const float* __restrict__ a2, const float* __restrict__ v2,
    unsigned short* __restrict__ Bcat, unsigned short* __restrict__ w2t,
    unsigned short* __restrict__ a2t, unsigned short* __restrict__ v2t)
{
  const int r = blockIdx.x >> 5, i = blockIdx.x & 31;
  const float* in; unsigned short* out; int Kd, Nd, ors, bx, by;
  switch (r) {
    case 0:  in = w1; out = Bcat;             Kd = 2048; Nd = 64;   ors = 2048; bx = 0; by = i; break;
    case 1:  in = a1; out = Bcat + 64 * 2048; Kd = 2048; Nd = 64;   ors = 2048; bx = 0; by = i; break;
    case 2:  in = v1; out = Bcat + 128 * 2048; Kd = 2048; Nd = 32;  ors = 2048; bx = 0; by = i; break;
    case 3:  in = w2; out = w2t;              Kd = 64;   Nd = 2048; ors = 64;   bx = i; by = 0; break;
    case 4:  in = a2; out = a2t;              Kd = 64;   Nd = 2048; ors = 64;   bx = i; by = 0; break;
    default: in = v2; out = v2t;              Kd = 32;   Nd = 2048; ors = 32;   bx = i; by = 0; break;
  }
  __shared__ unsigned short tile[64][65];
  const int tx = threadIdx.x & 63, ty = threadIdx.x >> 6;
  const int n0 = bx * 64, k0 = by * 64;
  #pragma unroll
  for (int j = 0; j < 16; ++j) {
    const int k = k0 + j * 4 + ty;
    const int n = n0 + tx;
    unsigned short v = 0;
    if (k < Kd && n < Nd) v = f2b(in[(size_t)k * Nd + n]);
    tile[j * 4 + ty][tx] = v;
  }
  __syncthreads();
  #pragma unroll
  for (int j = 0; j < 16; ++j) {
    const int n = n0 + j * 4 + ty;
    const int k = k0 + tx;
    if (n < Nd && k < Kd) out[(size_t)n * ors + k] = tile[tx][j * 4 + ty];
  }
}

// ---------------------------------------------------------------------------
// bf16 MFMA GEMM body: C[M,N] = A[M,K] @ B[N,K]^T (+bias). 128x128 tile, BK=32.
// ---------------------------------------------------------------------------
template<int OUTBF16, int ACT>
__device__ __forceinline__ void gemm_body(
    const unsigned short* __restrict__ A, int lda,
    const unsigned short* __restrict__ B, int ldb,
    const float* __restrict__ bias, void* __restrict__ Cv, int ldc,
    int M, int N, int K, int row0, int col0)
{
  __shared__ __align__(16) unsigned short As[128 * 32];
  __shared__ __align__(16) unsigned short Bs[128 * 32];
  const int tid = threadIdx.x;
  const int w = tid >> 6, lane = tid & 63;
  const int wr = (w >> 1) * 64, wc = (w & 1) * 64;

  f32x4 acc[4][4];
  #pragma unroll
  for (int i = 0; i < 4; ++i)
    #pragma unroll
    for (int j = 0; j < 4; ++j)
      acc[i][j] = (f32x4){0.f, 0.f, 0.f, 0.f};

  const int srow = w * 32 + (lane >> 2);
  const int scol = (lane & 3) * 8;
  const int brow0 = (col0 + srow < N) ? (col0 + srow) : 0;
  const int brow1 = (col0 + srow + 16 < N) ? (col0 + srow + 16) : 0;
  const unsigned short* gA0 = A + (size_t)(row0 + srow) * lda + scol;
  const unsigned short* gA1 = gA0 + (size_t)16 * lda;
  const unsigned short* gB0 = B + (size_t)brow0 * ldb + scol;
  const unsigned short* gB1 = B + (size_t)brow1 * ldb + scol;
  unsigned short* lA0 = As + w * 1024;
  unsigned short* lA1 = As + w * 1024 + 512;
  unsigned short* lB0 = Bs + w * 1024;
  unsigned short* lB1 = Bs + w * 1024 + 512;

  const int m16 = lane & 15;
  const int q8  = (lane >> 4) * 8;

  for (int k0 = 0; k0 < K; k0 += 32) {
    async16(gA0, lA0);
    async16(gA1, lA1);
    async16(gB0, lB0);
    async16(gB1, lB1);
    gA0 += 32; gA1 += 32; gB0 += 32; gB1 += 32;
    __syncthreads();
    bf16x8 af[4], bfr[4];
    #pragma unroll
    for (int i = 0; i < 4; ++i) {
      af[i]  = *(const bf16x8*)(As + (wr + i * 16 + m16) * 32 + q8);
      bfr[i] = *(const bf16x8*)(Bs + (wc + i * 16 + m16) * 32 + q8);
    }
    #pragma unroll
    for (int i = 0; i < 4; ++i)
      #pragma unroll
      for (int j = 0; j < 4; ++j)
        acc[i][j] = __builtin_amdgcn_mfma_f32_16x16x32_bf16(af[i], bfr[j], acc[i][j], 0, 0, 0);
    __syncthreads();
  }

  #pragma unroll
  for (int j = 0; j < 4; ++j) {
    const int c_ = col0 + wc + j * 16 + (lane & 15);
    if (c_ < N) {
      const float bv = bias ? bias[c_] : 0.f;
      #pragma unroll
      for (int i = 0; i < 4; ++i) {
        const int r_ = row0 + wr + i * 16 + (lane >> 4) * 4;
        #pragma unroll
        for (int t4 = 0; t4 < 4; ++t4) {
          float v = acc[i][j][t4] + bv;
          if (ACT == 2 && c_ < 64) v = tanhf(v);
          if (OUTBF16)
            ((unsigned short*)Cv)[(size_t)(r_ + t4) * ldc + c_] = f2b(v);
          else
            ((float*)Cv)[(size_t)(r_ + t4) * ldc + c_] = v;
        }
      }
    }
  }
}

template<int OUTBF16, int ACT>
__global__ __launch_bounds__(256) void gemm_mfma(
    const unsigned short* __restrict__ A, int lda,
    const unsigned short* __restrict__ B, int ldb,
    const float* __restrict__ bias, void* __restrict__ Cv, int ldc,
    int M, int N, int K)
{
  gemm_body<OUTBF16, ACT>(A, lda, B, ldb, bias, Cv, ldc, M, N, K,
                          blockIdx.y * 128, blockIdx.x * 128);
}

// Merged low-rank stage-2: blockIdx.z selects (w | a | v) region.
__global__ __launch_bounds__(256) void gemm_lr2(
    const unsigned short* __restrict__ hcat,
    const unsigned short* __restrict__ w2t,
    const unsigned short* __restrict__ a2t,
    const unsigned short* __restrict__ v2t,
    float* __restrict__ wt, float* __restrict__ at, float* __restrict__ vt)
{
  const int z = blockIdx.z;
  const unsigned short* A; const unsigned short* Bm; float* C; int K;
  if (z == 0)      { A = hcat;       Bm = w2t; C = wt; K = 64; }
  else if (z == 1) { A = hcat + 64;  Bm = a2t; C = at; K = 64; }
  else             { A = hcat + 128; Bm = v2t; C = vt; K = 32; }
  gemm_body<0, 0>(A, 160, Bm, K, nullptr, C, 2048, 4096, 2048, K,
                  blockIdx.y * 128, blockIdx.x * 128);
}

// ---------------------------------------------------------------------------
// Merged R|K|V|H projection GEMM: B is RKVb||Bcat = (3232 x 2048) bf16,
// contiguous. Tiles 0..23 -> r/k/v (f32 + bias); tiles 24..25 -> hcat
// (bf16 out, tanh on first 64 cols). Absorbs the former lr1 launch.
// ---------------------------------------------------------------------------
__global__ __launch_bounds__(256) void gemm_rkvh(
    const unsigned short* __restrict__ A, const unsigned short* __restrict__ B,
    const float* __restrict__ Rb_, const float* __restrict__ Kb_,
    const float* __restrict__ Vb_,
    float* __restrict__ Cr, float* __restrict__ Ck, float* __restrict__ Cvv,
    unsigned short* __restrict__ hcat)
{
  const int col0 = blockIdx.x * 128;
  const int row0 = blockIdx.y * 128;
  float* Cf = nullptr; unsigned short* Ch = nullptr;
  int ldc, cbase; const float* bias = nullptr;
  if (col0 < 2048)      { Cf = Cr;  ldc = 2048; cbase = col0;        bias = Rb_; }
  else if (col0 < 2560) { Cf = Ck;  ldc = 512;  cbase = col0 - 2048; bias = Kb_; }
  else if (col0 < 3072) { Cf = Cvv; ldc = 512;  cbase = col0 - 2560; bias = Vb_; }
  else                  { Ch = hcat; ldc = 160; cbase = col0 - 3072; }

  __shared__ __align__(16) unsigned short As[128 * 32];
  __shared__ __align__(16) unsigned short Bs[128 * 32];
  const int tid = threadIdx.x;
  const int w = tid >> 6, lane = tid & 63;
  const int wr = (w >> 1) * 64, wc = (w & 1) * 64;

  f32x4 acc[4][4];
  #pragma unroll
  for (int i = 0; i < 4; ++i)
    #pragma unroll
    for (int j = 0; j < 4; ++j)
      acc[i][j] = (f32x4){0.f, 0.f, 0.f, 0.f};

  const int srow = w * 32 + (lane >> 2);
  const int scol = (lane & 3) * 8;
  const int brow0 = (col0 + srow < 3232) ? (col0 + srow) : 0;
  const int brow1 = (col0 + srow + 16 < 3232) ? (col0 + srow + 16) : 0;
  const unsigned short* gA0 = A + (size_t)(row0 + srow) * 2048 + scol;
  const unsigned short* gA1 = gA0 + (size_t)16 * 2048;
  const unsigned short* gB0 = B + (size_t)brow0 * 2048 + scol;
  const unsigned short* gB1 = B + (size_t)brow1 * 2048 + scol;
  unsigned short* lA0 = As + w * 1024;
  unsigned short* lA1 = As + w * 1024 + 512;
  unsigned short* lB0 = Bs + w * 1024;
  unsigned short* lB1 = Bs + w * 1024 + 512;

  const int m16 = lane & 15;
  const int q8  = (lane >> 4) * 8;

  for (int k0 = 0; k0 < 2048; k0 += 32) {
    async16(gA0, lA0);
    async16(gA1, lA1);
    async16(gB0, lB0);
    async16(gB1, lB1);
    gA0 += 32; gA1 += 32; gB0 += 32; gB1 += 32;
    __syncthreads();
    bf16x8 af[4], bfr[4];
    #pragma unroll
    for (int i = 0; i < 4; ++i) {
      af[i]  = *(const bf16x8*)(As + (wr + i * 16 + m16) * 32 + q8);
      bfr[i] = *(const bf16x8*)(Bs + (wc + i * 16 + m16) * 32 + q8);
    }
    #pragma unroll
    for (int i = 0; i < 4; ++i)
      #pragma unroll
      for (int j = 0; j < 4; ++j)
        acc[i][j] = __builtin_amdgcn_mfma_f32_16x16x32_bf16(af[i], bfr[j], acc[i][j], 0, 0, 0);
    __syncthreads();
  }

  #pragma unroll
  for (int j = 0; j < 4; ++j) {
    const int c_ = cbase + wc + j * 16 + (lane & 15);
    if (Ch) {
      if (c_ < 160) {
        #pragma unroll
        for (int i = 0; i < 4; ++i) {
          const int r_ = row0 + wr + i * 16 + (lane >> 4) * 4;
          #pragma unroll
          for (int t4 = 0; t4 < 4; ++t4) {
            float v = acc[i][j][t4];
            if (c_ < 64) v = tanhf(v);
            Ch[(size_t)(r_ + t4) * 160 + c_] = f2b(v);
          }
        }
      }
    } else {
      const float bv = bias[c_];
      #pragma unroll
      for (int i = 0; i < 4; ++i) {
        const int r_ = row0 + wr + i * 16 + (lane >> 4) * 4;
        #pragma unroll
        for (int t4 = 0; t4 < 4; ++t4)
          Cf[(size_t)(r_ + t4) * ldc + c_] = acc[i][j][t4] + bv;
      }
    }
  }
}

// ---------------------------------------------------------------------------
// Elementwise prep. Packs scan streams as f16 pairs (v_cvt_pkrtz):
//   rk_pk[idx] = [hi=f16(k_final) | lo=f16(r)]
//   ab_pk[idx] = [hi=f16(aa)      | lo=f16(bb)]
// decay (wt) and v_final (vt) stay f32 (decay compounds over 1024 steps).
// ---------------------------------------------------------------------------
__global__ __launch_bounds__(256) void prep_kernel(
    const float* __restrict__ k_buf, const float* __restrict__ v_buf,
    const float* __restrict__ r_buf,
    float* wt_decay, const float* __restrict__ at, float* vt_vf,
    const float* __restrict__ v_first,
    const float* __restrict__ w0, const float* __restrict__ a0,
    const float* __restrict__ v0, const float* __restrict__ k_k,
    const float* __restrict__ k_a,
    unsigned* __restrict__ rk_pk, unsigned* __restrict__ ab_pk)
{
  const int row = blockIdx.x;
  const int tid = threadIdx.x;
  const int c0 = tid << 3;
  const int h = tid >> 3;
  const int kvoff = (h >> 2) << 6;
  const size_t base = (size_t)row * 2048;
  const size_t kvrow = (size_t)row * 512;
  float kr[8], kkr[8];
  float ss = 0.f;
  #pragma unroll
  for (int e = 0; e < 8; ++e) {
    const int c = c0 + e;
    const float kv = k_buf[kvrow + kvoff + (c & 63)];
    kr[e] = kv;
    const float t = kv * k_k[c];
    kkr[e] = t;
    ss = fmaf(t, t, ss);
  }
  ss += __shfl_xor(ss, 1);
  ss += __shfl_xor(ss, 2);
  ss += __shfl_xor(ss, 4);
  const float inv = 1.f / fmaxf(sqrtf(ss), 1e-12f);
  #pragma unroll
  for (int e = 0; e < 8; ++e) {
    const int c = c0 + e;
    const size_t idx = base + c;
    const float kk = kkr[e] * inv;
    const float a = 1.f / (1.f + expf(-(a0[c] + at[idx])));
    const float u = w0[c] + wt_decay[idx];
    const float sig_u = 1.f / (1.f + expf(-u));
    wt_decay[idx] = expf(-0.5488116360940264f * sig_u);
    const float kfin = kr[e] * fmaf(a - 1.f, k_a[c], 1.f);
    const float vr = v_buf[kvrow + kvoff + (c & 63)];
    const float sv = 1.f / (1.f + expf(-(v0[c] + vt_vf[idx])));
    vt_vf[idx] = vr + (v_first[idx] - vr) * sv;
    const float bbv = kk * a;
    const float aav = -kk;
    unsigned rk_u, ab_u;
    asm("v_cvt_pkrtz_f16_f32 %0, %1, %2" : "=v"(rk_u) : "v"(r_buf[idx]), "v"(kfin));
    asm("v_cvt_pkrtz_f16_f32 %0, %1, %2" : "=v"(ab_u) : "v"(bbv), "v"(aav));
    rk_pk[idx] = rk_u;
    ab_pk[idx] = ab_u;
  }
}

// ---------------------------------------------------------------------------
// RWKV-7 scan — cooperative-LDS, f16-packed streams, 32-step chunks with an
// explicit 1-step LDS software pipeline inside PROCESS.
//
// Round-5 post-mortem: VGPR=44 showed the compiler scheduled each step's
// ds_reads right before their uses -> LDS pipe idle during the DPP chains
// (507 cyc/step vs ~334 LDS-pipe floor). Fix: named prefetch registers for
// step s+1 loaded before computing step s, and 32-step chunks to halve
// barrier count. vmcnt ladder (STAGE=7 ops, YSTORE=2): WB(7) chunk0,
// WB(9) steady, WB(2) last. GroupNorm partials fused.
// ---------------------------------------------------------------------------
#define WB(n) asm volatile("s_waitcnt vmcnt(" #n ") lgkmcnt(0)\n\ts_barrier" ::: "memory")
#define BAR2() asm volatile("s_waitcnt lgkmcnt(0)\n\ts_barrier" ::: "memory")

__global__ __launch_bounds__(256) void scan_kernel(
    const unsigned* __restrict__ rkB, const unsigned* __restrict__ abB,
    const float* __restrict__ dB, const float* __restrict__ vB,
    const float* __restrict__ state, float* __restrict__ y,
    float* __restrict__ part)
{
  // LDS words: buf[p] at p*6656: rk[32][64] u32 at +0, ab at +2048,
  // d[32][64] f32 at +4096, v[32][16] f32 at +6144 (512).
  // y at 13312 ([32][16] = 512). Total 13824 words = 55296 B.
  __shared__ float lds[13824];
  unsigned* ldsU = (unsigned*)lds;
  const int tid = threadIdx.x;
  const int bid = blockIdx.x;
  const int xcd = bid & 7, bj = bid >> 3;
  const int m = bj & 3, gq = bj >> 2;
  const int bh = (gq << 3) | xcd;
  const int widx = tid >> 6;
  const int lane = tid & 63;
  const int rg = lane >> 4;
  const int colg = lane & 15;
  const int rowb = (widx << 2) + rg;       // head-row within quarter, [0,16)
  const int row = (m << 4) + rowb;         // head-row within head, [0,64)
  const int b = bh >> 5, h = bh & 31;

  float4 S = *(const float4*)(state + (size_t)bh * 4096 + row * 64 + (colg << 2));

  const unsigned cb = (unsigned)((b * 1024) * 2048 + h * 64);
  const unsigned srow8 = (unsigned)((widx << 3) + rg);  // staging step base
  const unsigned scol = (unsigned)(colg << 2);          // staging col word
  const unsigned sseg = (unsigned)(widx << 9);          // 512 words per wave

  float sacc = 0.f, ssacc = 0.f;
  const float fzero = 0.0f;

  #define STAGE(step0, bofs) do {                                            \
    const unsigned go0_ = cb + ((step0) + srow8) * 2048u + scol;             \
    const unsigned go1_ = go0_ + 4u * 2048u;                                 \
    async16(rkB + go0_, ldsU + (bofs) + sseg);                               \
    async16(rkB + go1_, ldsU + (bofs) + sseg + 256);                         \
    async16(abB + go0_, ldsU + (bofs) + 2048 + sseg);                        \
    async16(abB + go1_, ldsU + (bofs) + 2048 + sseg + 256);                  \
    async16(dB + go0_,  lds + (bofs) + 4096 + sseg);                         \
    async16(dB + go1_,  lds + (bofs) + 4096 + sseg + 256);                   \
    if (lane < 32) {                                                         \
      const unsigned gv_ = cb + ((step0) + (unsigned)(widx << 3)             \
                                 + (unsigned)(lane >> 2)) * 2048u            \
                           + (unsigned)(m << 4) + (unsigned)((lane & 3) << 2); \
      async16(vB + gv_, lds + (bofs) + 6144 + (widx << 7));                  \
    }                                                                        \
  } while (0)

  #define PROCESS(bofs) do {                                                 \
    uint4 rkw = *(const uint4*)(ldsU + (bofs) + (colg << 2));                \
    uint4 abw = *(const uint4*)(ldsU + (bofs) + 2048 + (colg << 2));         \
    float4 dvw = *(const float4*)(lds + (bofs) + 4096 + (colg << 2));        \
    float vvw = lds[(bofs) + 6144 + rowb];                                   \
    _Pragma("unroll")                                                        \
    for (int s = 0; s < 32; ++s) {                                           \
      const uint4 rkc = rkw;                                                 \
      const uint4 abc = abw;                                                 \
      const float4 dvc = dvw;                                                \
      const float vvc = vvw;                                                 \
      if (s < 31) {                                                          \
        rkw = *(const uint4*)(ldsU + (bofs) + (s + 1) * 64 + (colg << 2));   \
        abw = *(const uint4*)(ldsU + (bofs) + 2048 + (s + 1) * 64 + (colg << 2)); \
        dvw = *(const float4*)(lds + (bofs) + 4096 + (s + 1) * 64 + (colg << 2)); \
        vvw = lds[(bofs) + 6144 + ((s + 1) << 4) + rowb];                    \
      }                                                                      \
      float t0 = mixhi(S.x, abc.x, fzero);                                   \
      t0 = mixhi(S.y, abc.y, t0);                                            \
      t0 = mixhi(S.z, abc.z, t0);                                            \
      t0 = mixhi(S.w, abc.w, t0);                                            \
      const float sa = rowsum16(t0);                                         \
      float p0 = mixhi(vvc, rkc.x, fzero);                                   \
      float p1 = mixhi(vvc, rkc.y, fzero);                                   \
      float p2 = mixhi(vvc, rkc.z, fzero);                                   \
      float p3 = mixhi(vvc, rkc.w, fzero);                                   \
      p0 = mixlo(sa, abc.x, p0);                                             \
      p1 = mixlo(sa, abc.y, p1);                                             \
      p2 = mixlo(sa, abc.z, p2);                                             \
      p3 = mixlo(sa, abc.w, p3);                                             \
      S.x = fmaf(S.x, dvc.x, p0);                                            \
      S.y = fmaf(S.y, dvc.y, p1);                                            \
      S.z = fmaf(S.z, dvc.z, p2);                                            \
      S.w = fmaf(S.w, dvc.w, p3);                                            \
      float t1 = mixlo(S.x, rkc.x, fzero);                                   \
      t1 = mixlo(S.y, rkc.y, t1);                                            \
      t1 = mixlo(S.z, rkc.z, t1);                                            \
      t1 = mixlo(S.w, rkc.w, t1);                                            \
      const float yv = rowsum16(t1);                                         \
      if (colg == 0) {                                                       \
        lds[13312 + (s << 4) + rowb] = yv;                                   \
        sacc += yv;                                                          \
        ssacc = fmaf(yv, yv, ssacc);                                         \
      }                                                                      \
    }                                                                        \
  } while (0)

  #define YSTORE(step0) do {                                                 \
    const float y0_ = lds[13312 + tid];                                      \
    const float y1_ = lds[13312 + 256 + tid];                                \
    y[cb + ((step0) + (unsigned)(tid >> 4)) * 2048u +                        \
      (unsigned)(m << 4) + (unsigned)(tid & 15)] = y0_;                      \
    y[cb + ((step0) + 16u + (unsigned)(tid >> 4)) * 2048u +                  \
      (unsigned)(m << 4) + (unsigned)(tid & 15)] = y1_;                      \
  } while (0)

  STAGE(0u, 0);
  STAGE(32u, 6656);

  // chunk 0
  WB(7);
  PROCESS(0);
  BAR2();
  YSTORE(0u);
  STAGE(64u, 0);

  // chunks 1..30
  for (int c = 1; c <= 30; ++c) {
    const int bofs = (c & 1) ? 6656 : 0;
    WB(9);
    PROCESS(bofs);
    BAR2();
    YSTORE((unsigned)(c << 5));
    if (c < 30) STAGE((unsigned)((c + 2) << 5), bofs);
  }

  // chunk 31
  WB(2);
  PROCESS(6656);
  BAR2();
  YSTORE(992u);

  // groupnorm partial for this (bh, quarter m): valid in colg==0 lanes.
  sacc  += __shfl_xor(sacc, 16);
  sacc  += __shfl_xor(sacc, 32);
  ssacc += __shfl_xor(ssacc, 16);
  ssacc += __shfl_xor(ssacc, 32);
  __syncthreads();
  if (lane == 0) { lds[widx] = sacc; lds[4 + widx] = ssacc; }
  __syncthreads();
  if (tid == 0) {
    const float s_  = lds[0] + lds[1] + lds[2] + lds[3];
    const float ss_ = lds[4] + lds[5] + lds[6] + lds[7];
    ((float2*)part)[(bh << 2) + m] = make_float2(s_, ss_);
  }

  #undef STAGE
  #undef PROCESS
  #undef YSTORE
}

// ---------------------------------------------------------------------------
// GroupNorm pass B + bonus: per-(b,t) row, writes xx in bf16.
// r,k for the bonus come from the packed f16 rk stream.
// ---------------------------------------------------------------------------
__global__ __launch_bounds__(256) void gapply_kernel(
    const float* __restrict__ y, const unsigned* __restrict__ rkB,
    const float* __restrict__ vf,
    const float* __restrict__ part, const float* __restrict__ r_k,
    const float* __restrict__ ln_w, const float* __restrict__ ln_b,
    unsigned short* __restrict__ xxb)
{
  const int row = blockIdx.x;        // b*1024 + t
  const int b = row >> 10;
  const int tid = threadIdx.x;
  const int h = tid >> 3;
  const int bh = b * 32 + h;
  float s = 0.f, ss = 0.f;
  #pragma unroll
  for (int j = 0; j < 4; ++j) {
    const float2 pr = ((const float2*)part)[(bh << 2) + j];
    s += pr.x; ss += pr.y;
  }
  const float mean = s * (1.f / 65536.f);
  const float rstd = rsqrtf(ss * (1.f / 65536.f) - mean * mean + 0.00064f);
  const int c0 = tid << 3;
  const size_t base = (size_t)row * 2048 + c0;
  float yv[8], vv[8];
  float p = 0.f;
  #pragma unroll
  for (int e = 0; e < 8; ++e) {
    yv[e] = y[base + e];
    vv[e] = vf[base + e];
    const unsigned w_ = rkB[base + e];
    p = fmaf(h2f(w_ & 0xffffu) * h2f(w_ >> 16), r_k[c0 + e], p);
  }
  p += __shfl_xor(p, 1);
  p += __shfl_xor(p, 2);
  p += __shfl_xor(p, 4);
  #pragma unroll
  for (int e = 0; e < 8; ++e) {
    const float yn = (yv[e] - mean) * rstd;
    xxb[base + e] = f2b(fmaf(yn, ln_w[c0 + e], ln_b[c0 + e]) + p * vv[e]);
  }
}

// ---------------------------------------------------------------------------
extern "C" void kernel_launch(void* const* d_in, const int* in_sizes, int n_in,
                              void* d_out, int out_size, void* d_ws, size_t ws_size,
                              hipStream_t stream) {
  const float* x       = (const float*)d_in[0];
  const float* v_first = (const float*)d_in[1];
  const float* state   = (const float*)d_in[2];
  const float* Rw      = (const float*)d_in[3];
  const float* R_bias  = (const float*)d_in[4];
  const float* Kw      = (const float*)d_in[5];
  const float* K_bias  = (const float*)d_in[6];
  const float* Vw      = (const float*)d_in[7];
  const float* V_bias  = (const float*)d_in[8];
  const float* Ow      = (const float*)d_in[9];
  const float* O_bias  = (const float*)d_in[10];
  const float* w0      = (const float*)d_in[11];
  const float* w1      = (const float*)d_in[12];
  const float* w2      = (const float*)d_in[13];
  const float* a0      = (const float*)d_in[14];
  const float* a1      = (const float*)d_in[15];
  const float* a2      = (const float*)d_in[16];
  const float* v0      = (const float*)d_in[17];
  const float* v1      = (const float*)d_in[18];
  const float* v2      = (const float*)d_in[19];
  const float* k_k     = (const float*)d_in[20];
  const float* k_a     = (const float*)d_in[21];
  const float* r_k     = (const float*)d_in[22];
  const float* ln_w    = (const float*)d_in[23];
  const float* ln_b    = (const float*)d_in[24];

  float* ws = (float*)d_ws;
  float* r_buf = ws;                    // 8388608
  float* k_buf = r_buf + 8388608;       // 2097152
  float* v_buf = k_buf + 2097152;       // 2097152
  float* wt    = v_buf + 2097152;       // 8388608 (u -> decay in place, f32)
  float* at    = wt    + 8388608;       // 8388608 (a pre-act -> y after scan)
  float* vt    = at    + 8388608;       // 8388608 (v pre-act -> v_final, f32)
  float* kf    = vt    + 8388608;       // 8388608 (bf16 alias region)
  float* aaq   = kf    + 8388608;       // 8388608 -> rk_pk (u32)
  float* bbq   = aaq   + 8388608;       // 8388608 -> ab_pk (u32)
  float* part  = bbq   + 8388608;       // 2048 (gnorm partials)
  // bf16 aliases into the kf region (all 16B-aligned, disjoint):
  unsigned short* xb   = (unsigned short*)bbq;               // dead before prep
  unsigned short* RKVb = (unsigned short*)kf;                // [0 .. 3,145,728) fl
  unsigned short* Bcat = RKVb + 3072 * 2048;                 // contiguous after RKVb
  unsigned short* hcat = (unsigned short*)(kf + 3400000);    // 4096x160 bf16
  unsigned short* w2t  = (unsigned short*)(kf + 3800000);    // 2048x64
  unsigned short* a2t  = (unsigned short*)(kf + 3900000);    // 2048x64
  unsigned short* v2t  = (unsigned short*)(kf + 4000000);    // 2048x32
  unsigned short* Ob   = (unsigned short*)(kf + 4500000);    // 2048x2048 bf16
  unsigned* rk_pk      = (unsigned*)aaq;                     // packed f16 k|r
  unsigned* ab_pk      = (unsigned*)bbq;                     // packed f16 aa|bb
  unsigned short* xxb  = (unsigned short*)bbq;               // after scan

  dim3 blk(256);
  // ---- converts (x, R|K|V, Ow all in one launch) ----
  cvt4_kernel<<<18432, blk, 0, stream>>>(x, Rw, Kw, Vw, Ow, xb, RKVb, Ob);
  tcvt_all<<<192, blk, 0, stream>>>(w1, a1, v1, w2, a2, v2, Bcat, w2t, a2t, v2t);
  // ---- merged R|K|V|H projection (absorbs lr1) ----
  gemm_rkvh<<<dim3(26, 32), blk, 0, stream>>>(xb, RKVb, R_bias, K_bias, V_bias,
                                              r_buf, k_buf, v_buf, hcat);
  // ---- low-rank stage 2 (w|a|v merged into one launch) ----
  gemm_lr2<<<dim3(16, 32, 3), blk, 0, stream>>>(hcat, w2t, a2t, v2t, wt, at, vt);
  // ---- elementwise prep (writes packed f16 streams) ----
  prep_kernel<<<4096, blk, 0, stream>>>(k_buf, v_buf, r_buf, wt, at, vt, v_first,
                                        w0, a0, v0, k_k, k_a, rk_pk, ab_pk);
  // ---- recurrent scan (f16-packed + fma_mix + SW pipeline; y reuses `at`) ----
  float* ybuf = at;
  scan_kernel<<<512, blk, 0, stream>>>(rk_pk, ab_pk, wt, vt, state, ybuf, part);
  // ---- group norm pass B + bonus -> bf16 xx (into bbq; ab_pk dead) ----
  gapply_kernel<<<4096, blk, 0, stream>>>(ybuf, rk_pk, vt, part, r_k,
                                          ln_w, ln_b, xxb);
  // ---- output projection ----
  gemm_mfma<0,0><<<dim3(16, 32), blk, 0, stream>>>(xxb, 2048, Ob, 2048, O_bias,
                                                   (float*)d_out, 2048, 4096, 2048, 2048);
}

// Round 7
// 724.641 us; speedup vs baseline: 1.1360x; 1.0153x over previous
//
#include <hip/hip_runtime.h>
#include <hip/hip_bf16.h>
#include <math.h>

typedef __attribute__((ext_vector_type(8))) short bf16x8;
typedef __attribute__((ext_vector_type(4))) float f32x4;

__device__ __forceinline__ unsigned short f2b(float f) {
  unsigned u = __float_as_uint(f);
  unsigned r = (u + 0x7FFF + ((u >> 16) & 1)) >> 16;
  return (unsigned short)r;
}

__device__ __forceinline__ void async16(const void* g, void* l) {
  __builtin_amdgcn_global_load_lds(
      (const __attribute__((address_space(1))) unsigned int*)(g),
      (__attribute__((address_space(3))) unsigned int*)(l), 16, 0, 0);
}

// Sum across the 16 lanes of a DPP row (lanes 16k..16k+15) via row_ror.
__device__ __forceinline__ float rowsum16(float x) {
  x += __int_as_float(__builtin_amdgcn_update_dpp(0, __float_as_int(x), 0x121, 0xF, 0xF, false));
  x += __int_as_float(__builtin_amdgcn_update_dpp(0, __float_as_int(x), 0x122, 0xF, 0xF, false));
  x += __int_as_float(__builtin_amdgcn_update_dpp(0, __float_as_int(x), 0x124, 0xF, 0xF, false));
  x += __int_as_float(__builtin_amdgcn_update_dpp(0, __float_as_int(x), 0x128, 0xF, 0xF, false));
  return x;
}

// v_fma_mix_f32: d = a(f32) * f16half(pk) + c(f32). No unpack instructions.
__device__ __forceinline__ float mixhi(float a, unsigned pk, float c) {
  float d;
  asm("v_fma_mix_f32 %0, %1, %2, %3 op_sel:[0,1,0] op_sel_hi:[0,1,0]"
      : "=v"(d) : "v"(a), "v"(pk), "v"(c));
  return d;
}
__device__ __forceinline__ float mixlo(float a, unsigned pk, float c) {
  float d;
  asm("v_fma_mix_f32 %0, %1, %2, %3 op_sel:[0,0,0] op_sel_hi:[0,1,0]"
      : "=v"(d) : "v"(a), "v"(pk), "v"(c));
  return d;
}
__device__ __forceinline__ float h2f(unsigned h) {
  float f; asm("v_cvt_f32_f16 %0, %1" : "=v"(f) : "v"(h)); return f;
}

// ---------------------------------------------------------------------------
// fp32 -> bf16 converts: x, R|K|V (concatenated 3072x2048) AND Ow, all in one
// launch. Ob lives in the dead tail of the kf region so it can be written
// here at the start (deletes the separate cvt launch).
// ---------------------------------------------------------------------------
__global__ __launch_bounds__(256) void cvt4_kernel(
    const float* __restrict__ x, const float* __restrict__ R,
    const float* __restrict__ K, const float* __restrict__ V,
    const float* __restrict__ Ow,
    unsigned short* __restrict__ xb, unsigned short* __restrict__ RKVb,
    unsigned short* __restrict__ Ob)
{
  const int bid = blockIdx.x;
  const float* s; unsigned short* d; int i;
  if (bid < 8192)       { s = x; d = xb; i = bid * 256 + threadIdx.x; }
  else if (bid < 12288) { s = R; d = RKVb; i = (bid - 8192) * 256 + threadIdx.x; }
  else if (bid < 13312) { s = K; d = RKVb + 2048 * 2048; i = (bid - 12288) * 256 + threadIdx.x; }
  else if (bid < 14336) { s = V; d = RKVb + 2560 * 2048; i = (bid - 13312) * 256 + threadIdx.x; }
  else                  { s = Ow; d = Ob; i = (bid - 14336) * 256 + threadIdx.x; }
  float4 v = ((const float4*)s)[i];
  ushort4 o;
  o.x = f2b(v.x); o.y = f2b(v.y); o.z = f2b(v.z); o.w = f2b(v.w);
  ((ushort4*)d)[i] = o;
}

// ---------------------------------------------------------------------------
// Transposed converts, all 6 small matrices in ONE launch (192 blocks):
// out[n*ors + k] = bf16(in[k*Nd + n]).
// ---------------------------------------------------------------------------
__global__ __launch_bounds__(256) void tcvt_all(
    const float* __restrict__ w1, const float* __restrict__ a1,
    const float* __restrict__ v1, const float* __restrict__ w2,
    const float* __restrict__ a2, const float* __restrict__ v2,
    unsigned short* __restrict__ Bcat, unsigned short* __restrict__ w2t,
    unsigned short* __restrict__ a2t, unsigned short* __restrict__ v2t)
{
  const int r = blockIdx.x >> 5, i = blockIdx.x & 31;
  const float* in; unsigned short* out; int Kd, Nd, ors, bx, by;
  switch (r) {
    case 0:  in = w1; out = Bcat;             Kd = 2048; Nd = 64;   ors = 2048; bx = 0; by = i; break;
    case 1:  in = a1; out = Bcat + 64 * 2048; Kd = 2048; Nd = 64;   ors = 2048; bx = 0; by = i; break;
    case 2:  in = v1; out = Bcat + 128 * 2048; Kd = 2048; Nd = 32;  ors = 2048; bx = 0; by = i; break;
    case 3:  in = w2; out = w2t;              Kd = 64;   Nd = 2048; ors = 64;   bx = i; by = 0; break;
    case 4:  in = a2; out = a2t;              Kd = 64;   Nd = 2048; ors = 64;   bx = i; by = 0; break;
    default: in = v2; out = v2t;              Kd = 32;   Nd = 2048; ors = 32;   bx = i; by = 0; break;
  }
  __shared__ unsigned short tile[64][65];
  const int tx = threadIdx.x & 63, ty = threadIdx.x >> 6;
  const int n0 = bx * 64, k0 = by * 64;
  #pragma unroll
  for (int j = 0; j < 16; ++j) {
    const int k = k0 + j * 4 + ty;
    const int n = n0 + tx;
    unsigned short v = 0;
    if (k < Kd && n < Nd) v = f2b(in[(size_t)k * Nd + n]);
    tile[j * 4 + ty][tx] = v;
  }
  __syncthreads();
  #pragma unroll
  for (int j = 0; j < 16; ++j) {
    const int n = n0 + j * 4 + ty;
    const int k = k0 + tx;
    if (n < Nd && k < Kd) out[(size_t)n * ors + k] = tile[tx][j * 4 + ty];
  }
}

// ---------------------------------------------------------------------------
// bf16 MFMA GEMM body: C[M,N] = A[M,K] @ B[N,K]^T (+bias). 128x128 tile, BK=32.
// ---------------------------------------------------------------------------
template<int OUTBF16, int ACT>
__device__ __forceinline__ void gemm_body(
    const unsigned short* __restrict__ A, int lda,
    const unsigned short* __restrict__ B, int ldb,
    const float* __restrict__ bias, void* __restrict__ Cv, int ldc,
    int M, int N, int K, int row0, int col0)
{
  __shared__ __align__(16) unsigned short As[128 * 32];
  __shared__ __align__(16) unsigned short Bs[128 * 32];
  const int tid = threadIdx.x;
  const int w = tid >> 6, lane = tid & 63;
  const int wr = (w >> 1) * 64, wc = (w & 1) * 64;

  f32x4 acc[4][4];
  #pragma unroll
  for (int i = 0; i < 4; ++i)
    #pragma unroll
    for (int j = 0; j < 4; ++j)
      acc[i][j] = (f32x4){0.f, 0.f, 0.f, 0.f};

  const int srow = w * 32 + (lane >> 2);
  const int scol = (lane & 3) * 8;
  const int brow0 = (col0 + srow < N) ? (col0 + srow) : 0;
  const int brow1 = (col0 + srow + 16 < N) ? (col0 + srow + 16) : 0;
  const unsigned short* gA0 = A + (size_t)(row0 + srow) * lda + scol;
  const unsigned short* gA1 = gA0 + (size_t)16 * lda;
  const unsigned short* gB0 = B + (size_t)brow0 * ldb + scol;
  const unsigned short* gB1 = B + (size_t)brow1 * ldb + scol;
  unsigned short* lA0 = As + w * 1024;
  unsigned short* lA1 = As + w * 1024 + 512;
  unsigned short* lB0 = Bs + w * 1024;
  unsigned short* lB1 = Bs + w * 1024 + 512;

  const int m16 = lane & 15;
  const int q8  = (lane >> 4) * 8;

  for (int k0 = 0; k0 < K; k0 += 32) {
    async16(gA0, lA0);
    async16(gA1, lA1);
    async16(gB0, lB0);
    async16(gB1, lB1);
    gA0 += 32; gA1 += 32; gB0 += 32; gB1 += 32;
    __syncthreads();
    bf16x8 af[4], bfr[4];
    #pragma unroll
    for (int i = 0; i < 4; ++i) {
      af[i]  = *(const bf16x8*)(As + (wr + i * 16 + m16) * 32 + q8);
      bfr[i] = *(const bf16x8*)(Bs + (wc + i * 16 + m16) * 32 + q8);
    }
    #pragma unroll
    for (int i = 0; i < 4; ++i)
      #pragma unroll
      for (int j = 0; j < 4; ++j)
        acc[i][j] = __builtin_amdgcn_mfma_f32_16x16x32_bf16(af[i], bfr[j], acc[i][j], 0, 0, 0);
    __syncthreads();
  }

  #pragma unroll
  for (int j = 0; j < 4; ++j) {
    const int c_ = col0 + wc + j * 16 + (lane & 15);
    if (c_ < N) {
      const float bv = bias ? bias[c_] : 0.f;
      #pragma unroll
      for (int i = 0; i < 4; ++i) {
        const int r_ = row0 + wr + i * 16 + (lane >> 4) * 4;
        #pragma unroll
        for (int t4 = 0; t4 < 4; ++t4) {
          float v = acc[i][j][t4] + bv;
          if (ACT == 2 && c_ < 64) v = tanhf(v);
          if (OUTBF16)
            ((unsigned short*)Cv)[(size_t)(r_ + t4) * ldc + c_] = f2b(v);
          else
            ((float*)Cv)[(size_t)(r_ + t4) * ldc + c_] = v;
        }
      }
    }
  }
}

template<int OUTBF16, int ACT>
__global__ __launch_bounds__(256) void gemm_mfma(
    const unsigned short* __restrict__ A, int lda,
    const unsigned short* __restrict__ B, int ldb,
    const float* __restrict__ bias, void* __restrict__ Cv, int ldc,
    int M, int N, int K)
{
  gemm_body<OUTBF16, ACT>(A, lda, B, ldb, bias, Cv, ldc, M, N, K,
                          blockIdx.y * 128, blockIdx.x * 128);
}

// Merged low-rank stage-2: blockIdx.z selects (w | a | v) region.
__global__ __launch_bounds__(256) void gemm_lr2(
    const unsigned short* __restrict__ hcat,
    const unsigned short* __restrict__ w2t,
    const unsigned short* __restrict__ a2t,
    const unsigned short* __restrict__ v2t,
    float* __restrict__ wt, float* __restrict__ at, float* __restrict__ vt)
{
  const int z = blockIdx.z;
  const unsigned short* A; const unsigned short* Bm; float* C; int K;
  if (z == 0)      { A = hcat;       Bm = w2t; C = wt; K = 64; }
  else if (z == 1) { A = hcat + 64;  Bm = a2t; C = at; K = 64; }
  else             { A = hcat + 128; Bm = v2t; C = vt; K = 32; }
  gemm_body<0, 0>(A, 160, Bm, K, nullptr, C, 2048, 4096, 2048, K,
                  blockIdx.y * 128, blockIdx.x * 128);
}

// ---------------------------------------------------------------------------
// Merged R|K|V|H projection GEMM: B is RKVb||Bcat = (3232 x 2048) bf16,
// contiguous. Tiles 0..23 -> r/k/v (f32 + bias); tiles 24..25 -> hcat
// (bf16 out, tanh on first 64 cols). Absorbs the former lr1 launch.
// ---------------------------------------------------------------------------
__global__ __launch_bounds__(256) void gemm_rkvh(
    const unsigned short* __restrict__ A, const unsigned short* __restrict__ B,
    const float* __restrict__ Rb_, const float* __restrict__ Kb_,
    const float* __restrict__ Vb_,
    float* __restrict__ Cr, float* __restrict__ Ck, float* __restrict__ Cvv,
    unsigned short* __restrict__ hcat)
{
  const int col0 = blockIdx.x * 128;
  const int row0 = blockIdx.y * 128;
  float* Cf = nullptr; unsigned short* Ch = nullptr;
  int ldc, cbase; const float* bias = nullptr;
  if (col0 < 2048)      { Cf = Cr;  ldc = 2048; cbase = col0;        bias = Rb_; }
  else if (col0 < 2560) { Cf = Ck;  ldc = 512;  cbase = col0 - 2048; bias = Kb_; }
  else if (col0 < 3072) { Cf = Cvv; ldc = 512;  cbase = col0 - 2560; bias = Vb_; }
  else                  { Ch = hcat; ldc = 160; cbase = col0 - 3072; }

  __shared__ __align__(16) unsigned short As[128 * 32];
  __shared__ __align__(16) unsigned short Bs[128 * 32];
  const int tid = threadIdx.x;
  const int w = tid >> 6, lane = tid & 63;
  const int wr = (w >> 1) * 64, wc = (w & 1) * 64;

  f32x4 acc[4][4];
  #pragma unroll
  for (int i = 0; i < 4; ++i)
    #pragma unroll
    for (int j = 0; j < 4; ++j)
      acc[i][j] = (f32x4){0.f, 0.f, 0.f, 0.f};

  const int srow = w * 32 + (lane >> 2);
  const int scol = (lane & 3) * 8;
  const int brow0 = (col0 + srow < 3232) ? (col0 + srow) : 0;
  const int brow1 = (col0 + srow + 16 < 3232) ? (col0 + srow + 16) : 0;
  const unsigned short* gA0 = A + (size_t)(row0 + srow) * 2048 + scol;
  const unsigned short* gA1 = gA0 + (size_t)16 * 2048;
  const unsigned short* gB0 = B + (size_t)brow0 * 2048 + scol;
  const unsigned short* gB1 = B + (size_t)brow1 * 2048 + scol;
  unsigned short* lA0 = As + w * 1024;
  unsigned short* lA1 = As + w * 1024 + 512;
  unsigned short* lB0 = Bs + w * 1024;
  unsigned short* lB1 = Bs + w * 1024 + 512;

  const int m16 = lane & 15;
  const int q8  = (lane >> 4) * 8;

  for (int k0 = 0; k0 < 2048; k0 += 32) {
    async16(gA0, lA0);
    async16(gA1, lA1);
    async16(gB0, lB0);
    async16(gB1, lB1);
    gA0 += 32; gA1 += 32; gB0 += 32; gB1 += 32;
    __syncthreads();
    bf16x8 af[4], bfr[4];
    #pragma unroll
    for (int i = 0; i < 4; ++i) {
      af[i]  = *(const bf16x8*)(As + (wr + i * 16 + m16) * 32 + q8);
      bfr[i] = *(const bf16x8*)(Bs + (wc + i * 16 + m16) * 32 + q8);
    }
    #pragma unroll
    for (int i = 0; i < 4; ++i)
      #pragma unroll
      for (int j = 0; j < 4; ++j)
        acc[i][j] = __builtin_amdgcn_mfma_f32_16x16x32_bf16(af[i], bfr[j], acc[i][j], 0, 0, 0);
    __syncthreads();
  }

  #pragma unroll
  for (int j = 0; j < 4; ++j) {
    const int c_ = cbase + wc + j * 16 + (lane & 15);
    if (Ch) {
      if (c_ < 160) {
        #pragma unroll
        for (int i = 0; i < 4; ++i) {
          const int r_ = row0 + wr + i * 16 + (lane >> 4) * 4;
          #pragma unroll
          for (int t4 = 0; t4 < 4; ++t4) {
            float v = acc[i][j][t4];
            if (c_ < 64) v = tanhf(v);
            Ch[(size_t)(r_ + t4) * 160 + c_] = f2b(v);
          }
        }
      }
    } else {
      const float bv = bias[c_];
      #pragma unroll
      for (int i = 0; i < 4; ++i) {
        const int r_ = row0 + wr + i * 16 + (lane >> 4) * 4;
        #pragma unroll
        for (int t4 = 0; t4 < 4; ++t4)
          Cf[(size_t)(r_ + t4) * ldc + c_] = acc[i][j][t4] + bv;
      }
    }
  }
}

// ---------------------------------------------------------------------------
// Elementwise prep. Packs scan streams as f16 pairs (v_cvt_pkrtz):
//   rk_pk[idx] = [hi=f16(k_final) | lo=f16(r)]
//   ab_pk[idx] = [hi=f16(aa)      | lo=f16(bb)]
// decay (wt) and v_final (vt) stay f32 (decay compounds over 1024 steps).
// ---------------------------------------------------------------------------
__global__ __launch_bounds__(256) void prep_kernel(
    const float* __restrict__ k_buf, const float* __restrict__ v_buf,
    const float* __restrict__ r_buf,
    float* wt_decay, const float* __restrict__ at, float* vt_vf,
    const float* __restrict__ v_first,
    const float* __restrict__ w0, const float* __restrict__ a0,
    const float* __restrict__ v0, const float* __restrict__ k_k,
    const float* __restrict__ k_a,
    unsigned* __restrict__ rk_pk, unsigned* __restrict__ ab_pk)
{
  const int row = blockIdx.x;
  const int tid = threadIdx.x;
  const int c0 = tid << 3;
  const int h = tid >> 3;
  const int kvoff = (h >> 2) << 6;
  const size_t base = (size_t)row * 2048;
  const size_t kvrow = (size_t)row * 512;
  float kr[8], kkr[8];
  float ss = 0.f;
  #pragma unroll
  for (int e = 0; e < 8; ++e) {
    const int c = c0 + e;
    const float kv = k_buf[kvrow + kvoff + (c & 63)];
    kr[e] = kv;
    const float t = kv * k_k[c];
    kkr[e] = t;
    ss = fmaf(t, t, ss);
  }
  ss += __shfl_xor(ss, 1);
  ss += __shfl_xor(ss, 2);
  ss += __shfl_xor(ss, 4);
  const float inv = 1.f / fmaxf(sqrtf(ss), 1e-12f);
  #pragma unroll
  for (int e = 0; e < 8; ++e) {
    const int c = c0 + e;
    const size_t idx = base + c;
    const float kk = kkr[e] * inv;
    const float a = 1.f / (1.f + expf(-(a0[c] + at[idx])));
    const float u = w0[c] + wt_decay[idx];
    const float sig_u = 1.f / (1.f + expf(-u));
    wt_decay[idx] = expf(-0.5488116360940264f * sig_u);
    const float kfin = kr[e] * fmaf(a - 1.f, k_a[c], 1.f);
    const float vr = v_buf[kvrow + kvoff + (c & 63)];
    const float sv = 1.f / (1.f + expf(-(v0[c] + vt_vf[idx])));
    vt_vf[idx] = vr + (v_first[idx] - vr) * sv;
    const float bbv = kk * a;
    const float aav = -kk;
    unsigned rk_u, ab_u;
    asm("v_cvt_pkrtz_f16_f32 %0, %1, %2" : "=v"(rk_u) : "v"(r_buf[idx]), "v"(kfin));
    asm("v_cvt_pkrtz_f16_f32 %0, %1, %2" : "=v"(ab_u) : "v"(bbv), "v"(aav));
    rk_pk[idx] = rk_u;
    ab_pk[idx] = ab_u;
  }
}

// ---------------------------------------------------------------------------
// RWKV-7 scan — cooperative-LDS, f16-packed streams, 32-step chunks with a
// DEPTH-2 LDS software pipeline inside PROCESS (named even/odd slots, all
// selections compile-time after full unroll).
//
// Round-6 post-mortem: 1-step prefetch (~100 cyc of compute cover) did not
// cover ds_read latency under 8-wave contention (~120-150 cyc) -> each step
// still stalled at its head lgkmcnt. Depth-2 gives ~200 cyc cover.
// vmcnt ladder unchanged (STAGE=7 ops, YSTORE=2): WB(7) chunk0, WB(9)
// steady, WB(2) last. GroupNorm partials fused.
// ---------------------------------------------------------------------------
#define WB(n) asm volatile("s_waitcnt vmcnt(" #n ") lgkmcnt(0)\n\ts_barrier" ::: "memory")
#define BAR2() asm volatile("s_waitcnt lgkmcnt(0)\n\ts_barrier" ::: "memory")

__global__ __launch_bounds__(256) void scan_kernel(
    const unsigned* __restrict__ rkB, const unsigned* __restrict__ abB,
    const float* __restrict__ dB, const float* __restrict__ vB,
    const float* __restrict__ state, float* __restrict__ y,
    float* __restrict__ part)
{
  // LDS words: buf[p] at p*6656: rk[32][64] u32 at +0, ab at +2048,
  // d[32][64] f32 at +4096, v[32][16] f32 at +6144 (512).
  // y at 13312 ([32][16] = 512). Total 13824 words = 55296 B.
  __shared__ float lds[13824];
  unsigned* ldsU = (unsigned*)lds;
  const int tid = threadIdx.x;
  const int bid = blockIdx.x;
  const int xcd = bid & 7, bj = bid >> 3;
  const int m = bj & 3, gq = bj >> 2;
  const int bh = (gq << 3) | xcd;
  const int widx = tid >> 6;
  const int lane = tid & 63;
  const int rg = lane >> 4;
  const int colg = lane & 15;
  const int rowb = (widx << 2) + rg;       // head-row within quarter, [0,16)
  const int row = (m << 4) + rowb;         // head-row within head, [0,64)
  const int b = bh >> 5, h = bh & 31;

  float4 S = *(const float4*)(state + (size_t)bh * 4096 + row * 64 + (colg << 2));

  const unsigned cb = (unsigned)((b * 1024) * 2048 + h * 64);
  const unsigned srow8 = (unsigned)((widx << 3) + rg);  // staging step base
  const unsigned scol = (unsigned)(colg << 2);          // staging col word
  const unsigned sseg = (unsigned)(widx << 9);          // 512 words per wave

  float sacc = 0.f, ssacc = 0.f;
  const float fzero = 0.0f;

  #define STAGE(step0, bofs) do {                                            \
    const unsigned go0_ = cb + ((step0) + srow8) * 2048u + scol;             \
    const unsigned go1_ = go0_ + 4u * 2048u;                                 \
    async16(rkB + go0_, ldsU + (bofs) + sseg);                               \
    async16(rkB + go1_, ldsU + (bofs) + sseg + 256);                         \
    async16(abB + go0_, ldsU + (bofs) + 2048 + sseg);                        \
    async16(abB + go1_, ldsU + (bofs) + 2048 + sseg + 256);                  \
    async16(dB + go0_,  lds + (bofs) + 4096 + sseg);                         \
    async16(dB + go1_,  lds + (bofs) + 4096 + sseg + 256);                   \
    if (lane < 32) {                                                         \
      const unsigned gv_ = cb + ((step0) + (unsigned)(widx << 3)             \
                                 + (unsigned)(lane >> 2)) * 2048u            \
                           + (unsigned)(m << 4) + (unsigned)((lane & 3) << 2); \
      async16(vB + gv_, lds + (bofs) + 6144 + (widx << 7));                  \
    }                                                                        \
  } while (0)

  #define LDRK(bofs, s) (*(const uint4*)(ldsU + (bofs) + (s) * 64 + (colg << 2)))
  #define LDAB(bofs, s) (*(const uint4*)(ldsU + (bofs) + 2048 + (s) * 64 + (colg << 2)))
  #define LDD(bofs, s)  (*(const float4*)(lds + (bofs) + 4096 + (s) * 64 + (colg << 2)))
  #define LDV(bofs, s)  (lds[(bofs) + 6144 + ((s) << 4) + rowb])

  #define PROCESS(bofs) do {                                                 \
    uint4 rk0 = LDRK(bofs, 0), ab0 = LDAB(bofs, 0);                          \
    float4 dv0 = LDD(bofs, 0); float vv0 = LDV(bofs, 0);                     \
    uint4 rk1 = LDRK(bofs, 1), ab1 = LDAB(bofs, 1);                          \
    float4 dv1 = LDD(bofs, 1); float vv1 = LDV(bofs, 1);                     \
    _Pragma("unroll")                                                        \
    for (int s = 0; s < 32; ++s) {                                           \
      const bool ev = ((s & 1) == 0);                                        \
      const uint4 rkc = ev ? rk0 : rk1;                                      \
      const uint4 abc = ev ? ab0 : ab1;                                      \
      const float4 dvc = ev ? dv0 : dv1;                                     \
      const float vvc = ev ? vv0 : vv1;                                      \
      if (s < 30) {                                                          \
        if (ev) {                                                            \
          rk0 = LDRK(bofs, s + 2); ab0 = LDAB(bofs, s + 2);                  \
          dv0 = LDD(bofs, s + 2);  vv0 = LDV(bofs, s + 2);                   \
        } else {                                                             \
          rk1 = LDRK(bofs, s + 2); ab1 = LDAB(bofs, s + 2);                  \
          dv1 = LDD(bofs, s + 2);  vv1 = LDV(bofs, s + 2);                   \
        }                                                                    \
      }                                                                      \
      float t0 = mixhi(S.x, abc.x, fzero);                                   \
      t0 = mixhi(S.y, abc.y, t0);                                            \
      t0 = mixhi(S.z, abc.z, t0);                                            \
      t0 = mixhi(S.w, abc.w, t0);                                            \
      const float sa = rowsum16(t0);                                         \
      float p0 = mixhi(vvc, rkc.x, fzero);                                   \
      float p1 = mixhi(vvc, rkc.y, fzero);                                   \
      float p2 = mixhi(vvc, rkc.z, fzero);                                   \
      float p3 = mixhi(vvc, rkc.w, fzero);                                   \
      p0 = mixlo(sa, abc.x, p0);                                             \
      p1 = mixlo(sa, abc.y, p1);                                             \
      p2 = mixlo(sa, abc.z, p2);                                             \
      p3 = mixlo(sa, abc.w, p3);                                             \
      S.x = fmaf(S.x, dvc.x, p0);                                            \
      S.y = fmaf(S.y, dvc.y, p1);                                            \
      S.z = fmaf(S.z, dvc.z, p2);                                            \
      S.w = fmaf(S.w, dvc.w, p3);                                            \
      float t1 = mixlo(S.x, rkc.x, fzero);                                   \
      t1 = mixlo(S.y, rkc.y, t1);                                            \
      t1 = mixlo(S.z, rkc.z, t1);                                            \
      t1 = mixlo(S.w, rkc.w, t1);                                            \
      const float yv = rowsum16(t1);                                         \
      if (colg == 0) {                                                       \
        lds[13312 + (s << 4) + rowb] = yv;                                   \
        sacc += yv;                                                          \
        ssacc = fmaf(yv, yv, ssacc);                                         \
      }                                                                      \
    }                                                                        \
  } while (0)

  #define YSTORE(step0) do {                                                 \
    const float y0_ = lds[13312 + tid];                                      \
    const float y1_ = lds[13312 + 256 + tid];                                \
    y[cb + ((step0) + (unsigned)(tid >> 4)) * 2048u +                        \
      (unsigned)(m << 4) + (unsigned)(tid & 15)] = y0_;                      \
    y[cb + ((step0) + 16u + (unsigned)(tid >> 4)) * 2048u +                  \
      (unsigned)(m << 4) + (unsigned)(tid & 15)] = y1_;                      \
  } while (0)

  STAGE(0u, 0);
  STAGE(32u, 6656);

  // chunk 0
  WB(7);
  PROCESS(0);
  BAR2();
  YSTORE(0u);
  STAGE(64u, 0);

  // chunks 1..30
  for (int c = 1; c <= 30; ++c) {
    const int bofs = (c & 1) ? 6656 : 0;
    WB(9);
    PROCESS(bofs);
    BAR2();
    YSTORE((unsigned)(c << 5));
    if (c < 30) STAGE((unsigned)((c + 2) << 5), bofs);
  }

  // chunk 31
  WB(2);
  PROCESS(6656);
  BAR2();
  YSTORE(992u);

  // groupnorm partial for this (bh, quarter m): valid in colg==0 lanes.
  sacc  += __shfl_xor(sacc, 16);
  sacc  += __shfl_xor(sacc, 32);
  ssacc += __shfl_xor(ssacc, 16);
  ssacc += __shfl_xor(ssacc, 32);
  __syncthreads();
  if (lane == 0) { lds[widx] = sacc; lds[4 + widx] = ssacc; }
  __syncthreads();
  if (tid == 0) {
    const float s_  = lds[0] + lds[1] + lds[2] + lds[3];
    const float ss_ = lds[4] + lds[5] + lds[6] + lds[7];
    ((float2*)part)[(bh << 2) + m] = make_float2(s_, ss_);
  }

  #undef STAGE
  #undef PROCESS
  #undef YSTORE
  #undef LDRK
  #undef LDAB
  #undef LDD
  #undef LDV
}

// ---------------------------------------------------------------------------
// GroupNorm pass B + bonus: per-(b,t) row, writes xx in bf16.
// r,k for the bonus come from the packed f16 rk stream.
// ---------------------------------------------------------------------------
__global__ __launch_bounds__(256) void gapply_kernel(
    const float* __restrict__ y, const unsigned* __restrict__ rkB,
    const float* __restrict__ vf,
    const float* __restrict__ part, const float* __restrict__ r_k,
    const float* __restrict__ ln_w, const float* __restrict__ ln_b,
    unsigned short* __restrict__ xxb)
{
  const int row = blockIdx.x;        // b*1024 + t
  const int b = row >> 10;
  const int tid = threadIdx.x;
  const int h = tid >> 3;
  const int bh = b * 32 + h;
  float s = 0.f, ss = 0.f;
  #pragma unroll
  for (int j = 0; j < 4; ++j) {
    const float2 pr = ((const float2*)part)[(bh << 2) + j];
    s += pr.x; ss += pr.y;
  }
  const float mean = s * (1.f / 65536.f);
  const float rstd = rsqrtf(ss * (1.f / 65536.f) - mean * mean + 0.00064f);
  const int c0 = tid << 3;
  const size_t base = (size_t)row * 2048 + c0;
  float yv[8], vv[8];
  float p = 0.f;
  #pragma unroll
  for (int e = 0; e < 8; ++e) {
    yv[e] = y[base + e];
    vv[e] = vf[base + e];
    const unsigned w_ = rkB[base + e];
    p = fmaf(h2f(w_ & 0xffffu) * h2f(w_ >> 16), r_k[c0 + e], p);
  }
  p += __shfl_xor(p, 1);
  p += __shfl_xor(p, 2);
  p += __shfl_xor(p, 4);
  #pragma unroll
  for (int e = 0; e < 8; ++e) {
    const float yn = (yv[e] - mean) * rstd;
    xxb[base + e] = f2b(fmaf(yn, ln_w[c0 + e], ln_b[c0 + e]) + p * vv[e]);
  }
}

// ---------------------------------------------------------------------------
extern "C" void kernel_launch(void* const* d_in, const int* in_sizes, int n_in,
                              void* d_out, int out_size, void* d_ws, size_t ws_size,
                              hipStream_t stream) {
  const float* x       = (const float*)d_in[0];
  const float* v_first = (const float*)d_in[1];
  const float* state   = (const float*)d_in[2];
  const float* Rw      = (const float*)d_in[3];
  const float* R_bias  = (const float*)d_in[4];
  const float* Kw      = (const float*)d_in[5];
  const float* K_bias  = (const float*)d_in[6];
  const float* Vw      = (const float*)d_in[7];
  const float* V_bias  = (const float*)d_in[8];
  const float* Ow      = (const float*)d_in[9];
  const float* O_bias  = (const float*)d_in[10];
  const float* w0      = (const float*)d_in[11];
  const float* w1      = (const float*)d_in[12];
  const float* w2      = (const float*)d_in[13];
  const float* a0      = (const float*)d_in[14];
  const float* a1      = (const float*)d_in[15];
  const float* a2      = (const float*)d_in[16];
  const float* v0      = (const float*)d_in[17];
  const float* v1      = (const float*)d_in[18];
  const float* v2      = (const float*)d_in[19];
  const float* k_k     = (const float*)d_in[20];
  const float* k_a     = (const float*)d_in[21];
  const float* r_k     = (const float*)d_in[22];
  const float* ln_w    = (const float*)d_in[23];
  const float* ln_b    = (const float*)d_in[24];

  float* ws = (float*)d_ws;
  float* r_buf = ws;                    // 8388608
  float* k_buf = r_buf + 8388608;       // 2097152
  float* v_buf = k_buf + 2097152;       // 2097152
  float* wt    = v_buf + 2097152;       // 8388608 (u -> decay in place, f32)
  float* at    = wt    + 8388608;       // 8388608 (a pre-act -> y after scan)
  float* vt    = at    + 8388608;       // 8388608 (v pre-act -> v_final, f32)
  float* kf    = vt    + 8388608;       // 8388608 (bf16 alias region)
  float* aaq   = kf    + 8388608;       // 8388608 -> rk_pk (u32)
  float* bbq   = aaq   + 8388608;       // 8388608 -> ab_pk (u32)
  float* part  = bbq   + 8388608;       // 2048 (gnorm partials)
  // bf16 aliases into the kf region (all 16B-aligned, disjoint):
  unsigned short* xb   = (unsigned short*)bbq;               // dead before prep
  unsigned short* RKVb = (unsigned short*)kf;                // [0 .. 3,145,728) fl
  unsigned short* Bcat = RKVb + 3072 * 2048;                 // contiguous after RKVb
  unsigned short* hcat = (unsigned short*)(kf + 3400000);    // 4096x160 bf16
  unsigned short* w2t  = (unsigned short*)(kf + 3800000);    // 2048x64
  unsigned short* a2t  = (unsigned short*)(kf + 3900000);    // 2048x64
  unsigned short* v2t  = (unsigned short*)(kf + 4000000);    // 2048x32
  unsigned short* Ob   = (unsigned short*)(kf + 4500000);    // 2048x2048 bf16
  unsigned* rk_pk      = (unsigned*)aaq;                     // packed f16 k|r
  unsigned* ab_pk      = (unsigned*)bbq;                     // packed f16 aa|bb
  unsigned short* xxb  = (unsigned short*)bbq;               // after scan

  dim3 blk(256);
  // ---- converts (x, R|K|V, Ow all in one launch) ----
  cvt4_kernel<<<18432, blk, 0, stream>>>(x, Rw, Kw, Vw, Ow, xb, RKVb, Ob);
  tcvt_all<<<192, blk, 0, stream>>>(w1, a1, v1, w2, a2, v2, Bcat, w2t, a2t, v2t);
  // ---- merged R|K|V|H projection (absorbs lr1) ----
  gemm_rkvh<<<dim3(26, 32), blk, 0, stream>>>(xb, RKVb, R_bias, K_bias, V_bias,
                                              r_buf, k_buf, v_buf, hcat);
  // ---- low-rank stage 2 (w|a|v merged into one launch) ----
  gemm_lr2<<<dim3(16, 32, 3), blk, 0, stream>>>(hcat, w2t, a2t, v2t, wt, at, vt);
  // ---- elementwise prep (writes packed f16 streams) ----
  prep_kernel<<<4096, blk, 0, stream>>>(k_buf, v_buf, r_buf, wt, at, vt, v_first,
                                        w0, a0, v0, k_k, k_a, rk_pk, ab_pk);
  // ---- recurrent scan (depth-2 LDS pipeline; y reuses `at`) ----
  float* ybuf = at;
  scan_kernel<<<512, blk, 0, stream>>>(rk_pk, ab_pk, wt, vt, state, ybuf, part);
  // ---- group norm pass B + bonus -> bf16 xx (into bbq; ab_pk dead) ----
  gapply_kernel<<<4096, blk, 0, stream>>>(ybuf, rk_pk, vt, part, r_k,
                                          ln_w, ln_b, xxb);
  // ---- output projection ----
  gemm_mfma<0,0><<<dim3(16, 32), blk, 0, stream>>>(xxb, 2048, Ob, 2048, O_bias,
                                                   (float*)d_out, 2048, 4096, 2048, 2048);
}